// Round 10
// baseline (477.094 us; speedup 1.0000x reference)
//
#include <hip/hip_runtime.h>
#include <hip/hip_bf16.h>

#define NV 512
#define NB 128
#define NC 64

typedef float fv4 __attribute__((ext_vector_type(4)));
typedef float fv2 __attribute__((ext_vector_type(2)));
typedef float f32x4 __attribute__((ext_vector_type(4)));
typedef short bf8 __attribute__((ext_vector_type(8)));            // 8 bf16 (MFMA A/B frag)
typedef unsigned short u16x4 __attribute__((ext_vector_type(4)));
typedef unsigned short u16x8 __attribute__((ext_vector_type(8)));
typedef unsigned u32x2 __attribute__((ext_vector_type(2)));
typedef unsigned u32x4 __attribute__((ext_vector_type(4)));

// f32 -> bf16 RNE, scalar
__device__ __forceinline__ unsigned short f2bf(float f) {
  unsigned u = __builtin_bit_cast(unsigned, f);
  u += 0x7fffu + ((u >> 16) & 1u);
  return (unsigned short)(u >> 16);
}

// packed f32x2 -> bf16x2 (v_cvt_pk_bf16_f32)
__device__ __forceinline__ unsigned cvt2(float lo, float hi) {
  __hip_bfloat162 h = __float22bfloat162_rn(make_float2(lo, hi));
  unsigned r;
  __builtin_memcpy(&r, &h, sizeof(r));
  return r;
}

__device__ __forceinline__ bf8 pack8(fv4 a0, fv4 a1) {
  u32x4 r;
  r[0] = cvt2(a0[0], a0[1]);
  r[1] = cvt2(a0[2], a0[3]);
  r[2] = cvt2(a1[0], a1[1]);
  r[3] = cvt2(a1[2], a1[3]);
  return __builtin_bit_cast(bf8, r);
}

// panel: [64 cols][512 rows] bf16, 1KB per col; XOR swizzle on 16B granules
__device__ __forceinline__ int swzL(int c, int r) {
  return ((c << 10) + (r << 1)) ^ ((c & 7) << 4);
}
// fallback staging layout
__device__ __forceinline__ int swzC(int j, int ii) {
  return ((j << 6) + (ii << 1)) ^ ((j & 3) << 4);
}

__device__ __forceinline__ void gload_lds16(const void* g, void* l) {
  __builtin_amdgcn_global_load_lds(
      (const __attribute__((address_space(1))) unsigned int*)g,
      (__attribute__((address_space(3))) unsigned int*)l, 16, 0, 0);
}

// ---------------------------------------------------------------------------
// Convert kernels
// ---------------------------------------------------------------------------
__global__ __launch_bounds__(256, 4)
void conv_f32_bf16_kernel(const float* __restrict__ src, unsigned short* __restrict__ dst) {
  const size_t i8 = ((size_t)blockIdx.x * 256 + threadIdx.x) * 8;
  fv4 a0 = *(const fv4*)(src + i8);
  fv4 a1 = *(const fv4*)(src + i8 + 4);
  u32x4 r;
  r[0] = cvt2(a0[0], a0[1]); r[1] = cvt2(a0[2], a0[3]);
  r[2] = cvt2(a1[0], a1[1]); r[3] = cvt2(a1[2], a1[3]);
  *(u32x4*)(dst + i8) = r;
}

// chol f32 -> LR bf16 (row-major, optional) + LT bf16 (transposed)
__global__ __launch_bounds__(256, 4)
void convert_LT_kernel(const float* __restrict__ chol,
                       unsigned short* __restrict__ LT,
                       unsigned short* __restrict__ LR) {
  __shared__ unsigned short T[64][72];
  const int bid = blockIdx.x;
  const int b  = bid >> 6;
  const int t  = bid & 63;
  const int ti = t >> 3, tj = t & 7;

  const float* src = chol + ((size_t)b * NV + ti * 64) * NV + tj * 64;
  {
    const int r0 = threadIdx.x >> 4;
    const int c4 = (threadIdx.x & 15) * 4;
    #pragma unroll
    for (int p = 0; p < 4; ++p) {
      const int r = p * 16 + r0;
      fv4 v = *(const fv4*)(src + (size_t)r * NV + c4);
      T[c4 + 0][r] = f2bf(v[0]);
      T[c4 + 1][r] = f2bf(v[1]);
      T[c4 + 2][r] = f2bf(v[2]);
      T[c4 + 3][r] = f2bf(v[3]);
      if (LR) {
        u32x2 pk; pk[0] = cvt2(v[0], v[1]); pk[1] = cvt2(v[2], v[3]);
        *(u32x2*)(LR + ((size_t)b * NV + ti * 64 + r) * NV + tj * 64 + c4) = pk;
      }
    }
  }
  __syncthreads();
  unsigned short* dst = LT + ((size_t)b * NV + tj * 64) * NV + ti * 64;
  const int c  = threadIdx.x >> 2;
  const int k8 = (threadIdx.x & 3) * 16;
  u16x8 o0, o1;
  #pragma unroll
  for (int q = 0; q < 8; ++q) { o0[q] = T[c][k8 + q]; o1[q] = T[c][k8 + 8 + q]; }
  *(u16x8*)(dst + (size_t)c * NV + k8)     = o0;
  *(u16x8*)(dst + (size_t)c * NV + k8 + 8) = o1;
}

// ---------------------------------------------------------------------------
// v5 main kernel: 64KB LDS (single panel) -> 2 WGs/CU.
// Phase B: A and B both direct from global (B rows L1-resident).
// Phases C/D: A direct, B from the one LDS panel (T1 then phi).
// ---------------------------------------------------------------------------

// A direct + B direct (phase B)
__device__ __forceinline__ void phase_allglobal(const unsigned short* Abase,
                                                const unsigned short* Bbase, // = LTb + c0 rows
                                                f32x4 (&acc)[2][4],
                                                int w, int lr, int lq) {
  const unsigned short* rA0 = Abase + (size_t)(w * 32 + lr) * NV + lq * 8;
  const unsigned short* rA1 = rA0 + 16 * NV;
  const unsigned short* rB0 = Bbase + (size_t)lr * NV + lq * 8;   // +n*16KB as imm? no: per-n base
  #pragma unroll 4
  for (int t = 0; t < 16; ++t) {
    bf8 a0 = *(const bf8*)(rA0 + t * 32);
    bf8 a1 = *(const bf8*)(rA1 + t * 32);
    #pragma unroll
    for (int n = 0; n < 4; ++n) {
      bf8 bf = *(const bf8*)(rB0 + (size_t)(n * 16) * NV + t * 32);
      acc[0][n] = __builtin_amdgcn_mfma_f32_16x16x32_bf16(a0, bf, acc[0][n], 0, 0, 0);
      acc[1][n] = __builtin_amdgcn_mfma_f32_16x16x32_bf16(a1, bf, acc[1][n], 0, 0, 0);
    }
  }
}

// A direct + B from LDS panel (phases C, D)
__device__ __forceinline__ void phase_direct(const unsigned short* Abase,
                                             const char* panel,
                                             f32x4 (&acc)[2][4],
                                             int w, int lr, int lq) {
  const unsigned short* rA0 = Abase + (size_t)(w * 32 + lr) * NV + lq * 8;
  const unsigned short* rA1 = rA0 + 16 * NV;
  #pragma unroll 4
  for (int t = 0; t < 16; ++t) {
    const int kbase = t * 32 + lq * 8;
    bf8 a0 = *(const bf8*)(rA0 + t * 32);
    bf8 a1 = *(const bf8*)(rA1 + t * 32);
    bf8 bfr[4];
    #pragma unroll
    for (int n = 0; n < 4; ++n)
      bfr[n] = *(const bf8*)(panel + swzL(n * 16 + lr, kbase));
    #pragma unroll
    for (int n = 0; n < 4; ++n)
      acc[0][n] = __builtin_amdgcn_mfma_f32_16x16x32_bf16(a0, bfr[n], acc[0][n], 0, 0, 0);
    #pragma unroll
    for (int n = 0; n < 4; ++n)
      acc[1][n] = __builtin_amdgcn_mfma_f32_16x16x32_bf16(a1, bfr[n], acc[1][n], 0, 0, 0);
  }
}

__global__ __launch_bounds__(1024, 8)
void fused_cholTE_v5(const unsigned short* __restrict__ CV,
                     const unsigned short* __restrict__ LR,
                     const unsigned short* __restrict__ LT,
                     float* __restrict__ out) {
  __shared__ __align__(16) char H[65536];   // single panel: T1, then phi

  const int tid  = threadIdx.x;
  const int w    = tid >> 6;
  const int lane = tid & 63;
  const int lr   = lane & 15;
  const int lq   = lane >> 4;

  const int bid = blockIdx.x;
  const int xcd = bid & 7;
  const int s   = bid >> 3;
  const int b   = xcd * 16 + (s >> 3);
  const int c0  = (s & 7) * NC;

  const unsigned short* CVb = CV + (size_t)b * NV * NV;
  const unsigned short* LRb = LR + (size_t)b * NV * NV;
  const unsigned short* LTb = LT + (size_t)b * NV * NV;
  float*                Ob  = out + (size_t)b * NV * NV;

  f32x4 acc[2][4];

  // ---- Phase B: T1 = CV @ cholC ; both operands direct from global
  #pragma unroll
  for (int m = 0; m < 2; ++m)
    #pragma unroll
    for (int n = 0; n < 4; ++n) acc[m][n] = (f32x4)0.f;
  phase_allglobal(CVb, LTb + (size_t)c0 * NV, acc, w, lr, lq);

  // T1 -> H (panel format)
  #pragma unroll
  for (int m = 0; m < 2; ++m) {
    #pragma unroll
    for (int n = 0; n < 4; ++n) {
      f32x4 a = acc[m][n];
      u32x2 pk; pk[0] = cvt2(a[0], a[1]); pk[1] = cvt2(a[2], a[3]);
      *(u32x2*)(H + swzL(n * 16 + lr, w * 32 + m * 16 + lq * 4)) = pk;
    }
  }
  __syncthreads();   // barrier 1: T1 panel complete

  // ---- Phase C: phi = LT-rows @ T1 (masked)
  #pragma unroll
  for (int m = 0; m < 2; ++m)
    #pragma unroll
    for (int n = 0; n < 4; ++n) acc[m][n] = (f32x4)0.f;
  phase_direct(LTb, H, acc, w, lr, lq);
  __syncthreads();   // barrier 2: all waves done READING H (T1)

  // mask (strict lower=1, diag=0.5, upper=0); phi -> H (overwrite T1)
  #pragma unroll
  for (int jt = 0; jt < 2; ++jt) {
    #pragma unroll
    for (int n = 0; n < 4; ++n) {
      f32x4 a = acc[jt][n];
      const int gk = c0 + n * 16 + lr;
      const int j0 = w * 32 + jt * 16 + lq * 4;
      float f[4];
      #pragma unroll
      for (int q = 0; q < 4; ++q) {
        const int j = j0 + q;
        f[q] = (j > gk) ? a[q] : ((j == gk) ? 0.5f * a[q] : 0.f);
      }
      u32x2 pk; pk[0] = cvt2(f[0], f[1]); pk[1] = cvt2(f[2], f[3]);
      *(u32x2*)(H + swzL(n * 16 + lr, j0)) = pk;
    }
  }
  __syncthreads();   // barrier 3: phi panel complete

  // ---- Phase D: out = -LR @ phi
  #pragma unroll
  for (int m = 0; m < 2; ++m)
    #pragma unroll
    for (int n = 0; n < 4; ++n) acc[m][n] = (f32x4)0.f;
  phase_direct(LRb, H, acc, w, lr, lq);

  #pragma unroll
  for (int m = 0; m < 2; ++m) {
    const int i0 = w * 32 + m * 16 + lq * 4;
    #pragma unroll
    for (int n = 0; n < 4; ++n) {
      f32x4 a = acc[m][n];
      const int col = c0 + n * 16 + lr;
      #pragma unroll
      for (int q = 0; q < 4; ++q)
        Ob[(size_t)(i0 + q) * NV + col] = -a[q];
    }
  }
}

// ---------------------------------------------------------------------------
// LT-only fast path (R2 form) for 64MB <= ws < 192MB
// ---------------------------------------------------------------------------
__global__ __launch_bounds__(1024, 1)
void fused_cholTE_fast(const float* __restrict__ covTE,
                       const float* __restrict__ chol,
                       const unsigned short* __restrict__ LT,
                       float* __restrict__ out) {
  __shared__ __align__(16) char lds[131072];
  char* sB0 = lds;
  char* sB1 = lds + 65536;

  const int tid  = threadIdx.x;
  const int w    = tid >> 6;
  const int lane = tid & 63;
  const int lr   = lane & 15;
  const int lq   = lane >> 4;

  const int bid = blockIdx.x;
  const int xcd = bid & 7;
  const int s   = bid >> 3;
  const int b   = xcd * 16 + (s >> 3);
  const int c0  = (s & 7) * NC;

  const float*          Cb  = covTE + (size_t)b * NV * NV;
  const float*          Lb  = chol  + (size_t)b * NV * NV;
  const unsigned short* LTb = LT    + (size_t)b * NV * NV;
  float*                Ob  = out   + (size_t)b * NV * NV;

  #pragma unroll
  for (int cc = 0; cc < 4; ++cc) {
    const int c = cc * 16 + w;
    const unsigned short* src = LTb + (size_t)(c0 + c) * NV + ((lane ^ (c & 7)) * 8);
    gload_lds16(src, sB0 + c * 1024);
  }
  __syncthreads();

  f32x4 acc[2][4];
  #pragma unroll
  for (int m = 0; m < 2; ++m)
    #pragma unroll
    for (int n = 0; n < 4; ++n) acc[m][n] = (f32x4)0.f;

  for (int kb = 0; kb < 16; ++kb) {
    const int kbase = kb * 32 + lq * 8;
    bf8 bfr[4];
    #pragma unroll
    for (int n = 0; n < 4; ++n)
      bfr[n] = *(const bf8*)(sB0 + swzL(n * 16 + lr, kbase));
    #pragma unroll
    for (int m = 0; m < 2; ++m) {
      const float* p = Cb + (size_t)(w * 32 + m * 16 + lr) * NV + kbase;
      fv4 a0 = *(const fv4*)p;
      fv4 a1 = *(const fv4*)(p + 4);
      bf8 af = pack8(a0, a1);
      #pragma unroll
      for (int n = 0; n < 4; ++n)
        acc[m][n] = __builtin_amdgcn_mfma_f32_16x16x32_bf16(af, bfr[n], acc[m][n], 0, 0, 0);
    }
  }
  #pragma unroll
  for (int m = 0; m < 2; ++m) {
    #pragma unroll
    for (int n = 0; n < 4; ++n) {
      f32x4 a = acc[m][n];
      u32x2 pk; pk[0] = cvt2(a[0], a[1]); pk[1] = cvt2(a[2], a[3]);
      *(u32x2*)(sB1 + swzL(n * 16 + lr, w * 32 + m * 16 + lq * 4)) = pk;
    }
  }
  __syncthreads();

  #pragma unroll
  for (int m = 0; m < 2; ++m)
    #pragma unroll
    for (int n = 0; n < 4; ++n) acc[m][n] = (f32x4)0.f;

  for (int ib = 0; ib < 16; ++ib) {
    const int kbase = ib * 32 + lq * 8;
    bf8 bt[4];
    #pragma unroll
    for (int n = 0; n < 4; ++n)
      bt[n] = *(const bf8*)(sB1 + swzL(n * 16 + lr, kbase));
    #pragma unroll
    for (int jt = 0; jt < 2; ++jt) {
      bf8 af = *(const bf8*)(LTb + (size_t)(w * 32 + jt * 16 + lr) * NV + kbase);
      #pragma unroll
      for (int n = 0; n < 4; ++n)
        acc[jt][n] = __builtin_amdgcn_mfma_f32_16x16x32_bf16(af, bt[n], acc[jt][n], 0, 0, 0);
    }
  }
  #pragma unroll
  for (int jt = 0; jt < 2; ++jt) {
    #pragma unroll
    for (int n = 0; n < 4; ++n) {
      f32x4 a = acc[jt][n];
      const int gk = c0 + n * 16 + lr;
      const int j0 = w * 32 + jt * 16 + lq * 4;
      float f[4];
      #pragma unroll
      for (int q = 0; q < 4; ++q) {
        const int j = j0 + q;
        f[q] = (j > gk) ? a[q] : ((j == gk) ? 0.5f * a[q] : 0.f);
      }
      u32x2 pk; pk[0] = cvt2(f[0], f[1]); pk[1] = cvt2(f[2], f[3]);
      *(u32x2*)(sB0 + swzL(n * 16 + lr, j0)) = pk;
    }
  }
  __syncthreads();

  #pragma unroll
  for (int m = 0; m < 2; ++m)
    #pragma unroll
    for (int n = 0; n < 4; ++n) acc[m][n] = (f32x4)0.f;

  for (int kb = 0; kb < 16; ++kb) {
    const int kbase = kb * 32 + lq * 8;
    bf8 bp[4];
    #pragma unroll
    for (int n = 0; n < 4; ++n)
      bp[n] = *(const bf8*)(sB0 + swzL(n * 16 + lr, kbase));
    #pragma unroll
    for (int m = 0; m < 2; ++m) {
      const float* p = Lb + (size_t)(w * 32 + m * 16 + lr) * NV + kbase;
      fv4 a0 = *(const fv4*)p;
      fv4 a1 = *(const fv4*)(p + 4);
      bf8 af = pack8(a0, a1);
      #pragma unroll
      for (int n = 0; n < 4; ++n)
        acc[m][n] = __builtin_amdgcn_mfma_f32_16x16x32_bf16(af, bp[n], acc[m][n], 0, 0, 0);
    }
  }
  #pragma unroll
  for (int m = 0; m < 2; ++m) {
    const int i0 = w * 32 + m * 16 + lq * 4;
    #pragma unroll
    for (int n = 0; n < 4; ++n) {
      f32x4 a = acc[m][n];
      const int col = c0 + n * 16 + lr;
      #pragma unroll
      for (int q = 0; q < 4; ++q)
        Ob[(size_t)(i0 + q) * NV + col] = -a[q];
    }
  }
}

// ---------------------------------------------------------------------------
// No-workspace fallback (R1 form)
// ---------------------------------------------------------------------------
__global__ __launch_bounds__(1024, 1)
void fused_cholTE_fallback(const float* __restrict__ covTE,
                           const float* __restrict__ chol,
                           float* __restrict__ out) {
  __shared__ __align__(16) char lds[131072];
  char* sB0 = lds;
  char* sB1 = lds + 65536;
  char* sCh = lds;

  const int tid  = threadIdx.x;
  const int w    = tid >> 6;
  const int lane = tid & 63;
  const int lr   = lane & 15;
  const int lq   = lane >> 4;

  const int bid = blockIdx.x;
  const int xcd = bid & 7;
  const int s   = bid >> 3;
  const int b   = xcd * 16 + (s >> 3);
  const int c0  = (s & 7) * NC;

  const float* Cb = covTE + (size_t)b * NV * NV;
  const float* Lb = chol  + (size_t)b * NV * NV;
  float*       Ob = out   + (size_t)b * NV * NV;

  {
    const int rr = tid >> 4;
    const int cc = (tid & 15) * 4;
    #pragma unroll
    for (int p = 0; p < 8; ++p) {
      const int r = p * 64 + rr;
      fv4 v = *(const fv4*)(Lb + (size_t)r * NV + c0 + cc);
      *(unsigned short*)(sB0 + swzL(cc + 0, r)) = f2bf(v[0]);
      *(unsigned short*)(sB0 + swzL(cc + 1, r)) = f2bf(v[1]);
      *(unsigned short*)(sB0 + swzL(cc + 2, r)) = f2bf(v[2]);
      *(unsigned short*)(sB0 + swzL(cc + 3, r)) = f2bf(v[3]);
    }
  }
  __syncthreads();

  f32x4 acc[2][4];
  #pragma unroll
  for (int m = 0; m < 2; ++m)
    #pragma unroll
    for (int n = 0; n < 4; ++n) acc[m][n] = (f32x4)0.f;

  for (int kb = 0; kb < 16; ++kb) {
    const int kbase = kb * 32 + lq * 8;
    bf8 bfr[4];
    #pragma unroll
    for (int n = 0; n < 4; ++n)
      bfr[n] = *(const bf8*)(sB0 + swzL(n * 16 + lr, kbase));
    #pragma unroll
    for (int m = 0; m < 2; ++m) {
      const float* p = Cb + (size_t)(w * 32 + m * 16 + lr) * NV + kbase;
      fv4 a0 = *(const fv4*)p;
      fv4 a1 = *(const fv4*)(p + 4);
      bf8 af = pack8(a0, a1);
      #pragma unroll
      for (int n = 0; n < 4; ++n)
        acc[m][n] = __builtin_amdgcn_mfma_f32_16x16x32_bf16(af, bfr[n], acc[m][n], 0, 0, 0);
    }
  }
  #pragma unroll
  for (int m = 0; m < 2; ++m) {
    #pragma unroll
    for (int n = 0; n < 4; ++n) {
      f32x4 a = acc[m][n];
      u32x2 pk; pk[0] = cvt2(a[0], a[1]); pk[1] = cvt2(a[2], a[3]);
      *(u32x2*)(sB1 + swzL(n * 16 + lr, w * 32 + m * 16 + lq * 4)) = pk;
    }
  }
  __syncthreads();

  #pragma unroll
  for (int m = 0; m < 2; ++m)
    #pragma unroll
    for (int n = 0; n < 4; ++n) acc[m][n] = (f32x4)0.f;

  const int sj = (tid & 255) * 2;
  const int so = tid >> 8;

  fv2 raw[8];
  {
    const float* src = Lb + (size_t)(so * 8) * NV + sj;
    #pragma unroll
    for (int r = 0; r < 8; ++r) raw[r] = *(const fv2*)(src + (size_t)r * NV);
    u16x8 p0, p1;
    #pragma unroll
    for (int r = 0; r < 8; ++r) { p0[r] = f2bf(raw[r][0]); p1[r] = f2bf(raw[r][1]); }
    *(u16x8*)(sCh + swzC(sj + 0, so * 8)) = p0;
    *(u16x8*)(sCh + swzC(sj + 1, so * 8)) = p1;
  }
  __syncthreads();

  for (int ib = 0; ib < 16; ++ib) {
    if (ib + 1 < 16) {
      const float* src = Lb + (size_t)((ib + 1) * 32 + so * 8) * NV + sj;
      #pragma unroll
      for (int r = 0; r < 8; ++r) raw[r] = *(const fv2*)(src + (size_t)r * NV);
    }
    bf8 bt[4];
    #pragma unroll
    for (int n = 0; n < 4; ++n)
      bt[n] = *(const bf8*)(sB1 + swzL(n * 16 + lr, ib * 32 + lq * 8));
    #pragma unroll
    for (int jt = 0; jt < 2; ++jt) {
      bf8 af = *(const bf8*)(sCh + swzC(w * 32 + jt * 16 + lr, lq * 8));
      #pragma unroll
      for (int n = 0; n < 4; ++n)
        acc[jt][n] = __builtin_amdgcn_mfma_f32_16x16x32_bf16(af, bt[n], acc[jt][n], 0, 0, 0);
    }
    __syncthreads();
    if (ib + 1 < 16) {
      u16x8 p0, p1;
      #pragma unroll
      for (int r = 0; r < 8; ++r) { p0[r] = f2bf(raw[r][0]); p1[r] = f2bf(raw[r][1]); }
      *(u16x8*)(sCh + swzC(sj + 0, so * 8)) = p0;
      *(u16x8*)(sCh + swzC(sj + 1, so * 8)) = p1;
    }
    __syncthreads();
  }

  #pragma unroll
  for (int jt = 0; jt < 2; ++jt) {
    #pragma unroll
    for (int n = 0; n < 4; ++n) {
      f32x4 a = acc[jt][n];
      const int gk = c0 + n * 16 + lr;
      const int j0 = w * 32 + jt * 16 + lq * 4;
      float f[4];
      #pragma unroll
      for (int q = 0; q < 4; ++q) {
        const int j = j0 + q;
        f[q] = (j > gk) ? a[q] : ((j == gk) ? 0.5f * a[q] : 0.f);
      }
      u32x2 pk; pk[0] = cvt2(f[0], f[1]); pk[1] = cvt2(f[2], f[3]);
      *(u32x2*)(sB0 + swzL(n * 16 + lr, j0)) = pk;
    }
  }
  __syncthreads();

  #pragma unroll
  for (int m = 0; m < 2; ++m)
    #pragma unroll
    for (int n = 0; n < 4; ++n) acc[m][n] = (f32x4)0.f;

  for (int kb = 0; kb < 16; ++kb) {
    const int kbase = kb * 32 + lq * 8;
    bf8 bp[4];
    #pragma unroll
    for (int n = 0; n < 4; ++n)
      bp[n] = *(const bf8*)(sB0 + swzL(n * 16 + lr, kbase));
    #pragma unroll
    for (int m = 0; m < 2; ++m) {
      const float* p = Lb + (size_t)(w * 32 + m * 16 + lr) * NV + kbase;
      fv4 a0 = *(const fv4*)p;
      fv4 a1 = *(const fv4*)(p + 4);
      bf8 af = pack8(a0, a1);
      #pragma unroll
      for (int n = 0; n < 4; ++n)
        acc[m][n] = __builtin_amdgcn_mfma_f32_16x16x32_bf16(af, bp[n], acc[m][n], 0, 0, 0);
    }
  }
  #pragma unroll
  for (int m = 0; m < 2; ++m) {
    const int i0 = w * 32 + m * 16 + lq * 4;
    #pragma unroll
    for (int n = 0; n < 4; ++n) {
      f32x4 a = acc[m][n];
      const int col = c0 + n * 16 + lr;
      #pragma unroll
      for (int q = 0; q < 4; ++q)
        Ob[(size_t)(i0 + q) * NV + col] = -a[q];
    }
  }
}

extern "C" void kernel_launch(void* const* d_in, const int* in_sizes, int n_in,
                              void* d_out, int out_size, void* d_ws, size_t ws_size,
                              hipStream_t stream) {
  const float* muTE  = (const float*)d_in[0];
  const float* covTE = (const float*)d_in[1];
  const float* chol  = (const float*)d_in[2];
  float* out = (float*)d_out;

  (void)hipMemcpyAsync(out, muTE, (size_t)NB * NV * sizeof(float),
                       hipMemcpyDeviceToDevice, stream);

  float* cholTE = out + (size_t)NB * NV;
  const size_t nmat     = (size_t)NB * NV * NV;          // 33,554,432 elems
  const size_t lt_bytes = nmat * sizeof(unsigned short); // 64 MiB

  if (ws_size >= 3 * lt_bytes) {
    unsigned short* CV = (unsigned short*)d_ws;
    unsigned short* LR = CV + nmat;
    unsigned short* LT = LR + nmat;
    conv_f32_bf16_kernel<<<dim3(nmat / (256 * 8)), dim3(256), 0, stream>>>(covTE, CV);
    convert_LT_kernel<<<dim3(NB * 64), dim3(256), 0, stream>>>(chol, LT, LR);
    fused_cholTE_v5<<<dim3(NB * (NV / NC)), dim3(1024), 0, stream>>>(CV, LR, LT, cholTE);
  } else if (ws_size >= lt_bytes) {
    unsigned short* LT = (unsigned short*)d_ws;
    convert_LT_kernel<<<dim3(NB * 64), dim3(256), 0, stream>>>(chol, LT, nullptr);
    fused_cholTE_fast<<<dim3(NB * (NV / NC)), dim3(1024), 0, stream>>>(
        covTE, chol, LT, cholTE);
  } else {
    fused_cholTE_fallback<<<dim3(NB * (NV / NC)), dim3(1024), 0, stream>>>(
        covTE, chol, cholTE);
  }
}

// Round 11
// 383.520 us; speedup vs baseline: 1.2440x; 1.2440x over previous
//
#include <hip/hip_runtime.h>
#include <hip/hip_bf16.h>

#define NV 512
#define NB 128
#define NC 64

typedef float fv4 __attribute__((ext_vector_type(4)));
typedef float fv2 __attribute__((ext_vector_type(2)));
typedef float f32x4 __attribute__((ext_vector_type(4)));
typedef short bf8 __attribute__((ext_vector_type(8)));            // 8 bf16 (MFMA A/B frag)
typedef unsigned short u16x4 __attribute__((ext_vector_type(4)));
typedef unsigned short u16x8 __attribute__((ext_vector_type(8)));
typedef unsigned u32x2 __attribute__((ext_vector_type(2)));
typedef unsigned u32x4 __attribute__((ext_vector_type(4)));

// f32 -> bf16 RNE, scalar
__device__ __forceinline__ unsigned short f2bf(float f) {
  unsigned u = __builtin_bit_cast(unsigned, f);
  u += 0x7fffu + ((u >> 16) & 1u);
  return (unsigned short)(u >> 16);
}

// packed f32x2 -> bf16x2 (v_cvt_pk_bf16_f32)
__device__ __forceinline__ unsigned cvt2(float lo, float hi) {
  __hip_bfloat162 h = __float22bfloat162_rn(make_float2(lo, hi));
  unsigned r;
  __builtin_memcpy(&r, &h, sizeof(r));
  return r;
}

__device__ __forceinline__ bf8 pack8(fv4 a0, fv4 a1) {
  u32x4 r;
  r[0] = cvt2(a0[0], a0[1]);
  r[1] = cvt2(a0[2], a0[3]);
  r[2] = cvt2(a1[0], a1[1]);
  r[3] = cvt2(a1[2], a1[3]);
  return __builtin_bit_cast(bf8, r);
}

// panel: [64 cols][512 rows] bf16, 1KB per col; XOR swizzle on 16B granules
__device__ __forceinline__ int swzL(int c, int r) {
  return ((c << 10) + (r << 1)) ^ ((c & 7) << 4);
}
// fallback staging layout
__device__ __forceinline__ int swzC(int j, int ii) {
  return ((j << 6) + (ii << 1)) ^ ((j & 3) << 4);
}

__device__ __forceinline__ void gload_lds16(const void* g, void* l) {
  __builtin_amdgcn_global_load_lds(
      (const __attribute__((address_space(1))) unsigned int*)g,
      (__attribute__((address_space(3))) unsigned int*)l, 16, 0, 0);
}

// ---------------------------------------------------------------------------
// Convert kernels
// ---------------------------------------------------------------------------
__global__ __launch_bounds__(256, 4)
void conv_f32_bf16_kernel(const float* __restrict__ src, unsigned short* __restrict__ dst) {
  const size_t i8 = ((size_t)blockIdx.x * 256 + threadIdx.x) * 8;
  fv4 a0 = *(const fv4*)(src + i8);
  fv4 a1 = *(const fv4*)(src + i8 + 4);
  u32x4 r;
  r[0] = cvt2(a0[0], a0[1]); r[1] = cvt2(a0[2], a0[3]);
  r[2] = cvt2(a1[0], a1[1]); r[3] = cvt2(a1[2], a1[3]);
  *(u32x4*)(dst + i8) = r;
}

// chol f32 -> LR bf16 (row-major, optional) + LT bf16 (transposed)
__global__ __launch_bounds__(256, 4)
void convert_LT_kernel(const float* __restrict__ chol,
                       unsigned short* __restrict__ LT,
                       unsigned short* __restrict__ LR) {
  __shared__ unsigned short T[64][72];
  const int bid = blockIdx.x;
  const int b  = bid >> 6;
  const int t  = bid & 63;
  const int ti = t >> 3, tj = t & 7;

  const float* src = chol + ((size_t)b * NV + ti * 64) * NV + tj * 64;
  {
    const int r0 = threadIdx.x >> 4;
    const int c4 = (threadIdx.x & 15) * 4;
    #pragma unroll
    for (int p = 0; p < 4; ++p) {
      const int r = p * 16 + r0;
      fv4 v = *(const fv4*)(src + (size_t)r * NV + c4);
      T[c4 + 0][r] = f2bf(v[0]);
      T[c4 + 1][r] = f2bf(v[1]);
      T[c4 + 2][r] = f2bf(v[2]);
      T[c4 + 3][r] = f2bf(v[3]);
      if (LR) {
        u32x2 pk; pk[0] = cvt2(v[0], v[1]); pk[1] = cvt2(v[2], v[3]);
        *(u32x2*)(LR + ((size_t)b * NV + ti * 64 + r) * NV + tj * 64 + c4) = pk;
      }
    }
  }
  __syncthreads();
  unsigned short* dst = LT + ((size_t)b * NV + tj * 64) * NV + ti * 64;
  const int c  = threadIdx.x >> 2;
  const int k8 = (threadIdx.x & 3) * 16;
  u16x8 o0, o1;
  #pragma unroll
  for (int q = 0; q < 8; ++q) { o0[q] = T[c][k8 + q]; o1[q] = T[c][k8 + 8 + q]; }
  *(u16x8*)(dst + (size_t)c * NV + k8)     = o0;
  *(u16x8*)(dst + (size_t)c * NV + k8 + 8) = o1;
}

// ---------------------------------------------------------------------------
// v6 main kernel: v4 structure (all-bf16 operands, B-panels in LDS, A direct
// from global, 3 barriers total) with FULLY UNROLLED K-loops — one flat
// 16-step schedule per phase so the compiler can pipeline loads to the
// 128-VGPR budget. No sched_barrier, no setprio.
// ---------------------------------------------------------------------------
__device__ __forceinline__ void phase_direct(const unsigned short* Abase,
                                             const char* panel,
                                             f32x4 (&acc)[2][4],
                                             int w, int lr, int lq) {
  const unsigned short* rA0 = Abase + (size_t)(w * 32 + lr) * NV + lq * 8;
  const unsigned short* rA1 = rA0 + 16 * NV;
  #pragma unroll
  for (int t = 0; t < 16; ++t) {
    const int kbase = t * 32 + lq * 8;
    bf8 a0 = *(const bf8*)(rA0 + t * 32);
    bf8 a1 = *(const bf8*)(rA1 + t * 32);
    bf8 bfr[4];
    #pragma unroll
    for (int n = 0; n < 4; ++n)
      bfr[n] = *(const bf8*)(panel + swzL(n * 16 + lr, kbase));
    #pragma unroll
    for (int n = 0; n < 4; ++n)
      acc[0][n] = __builtin_amdgcn_mfma_f32_16x16x32_bf16(a0, bfr[n], acc[0][n], 0, 0, 0);
    #pragma unroll
    for (int n = 0; n < 4; ++n)
      acc[1][n] = __builtin_amdgcn_mfma_f32_16x16x32_bf16(a1, bfr[n], acc[1][n], 0, 0, 0);
  }
}

__global__ __launch_bounds__(1024, 1)
void fused_cholTE_v6(const unsigned short* __restrict__ CV,
                     const unsigned short* __restrict__ LR,
                     const unsigned short* __restrict__ LT,
                     float* __restrict__ out) {
  __shared__ __align__(16) char lds[131072];
  char* H0 = lds;            // phase B panel (cholC); then phi panel (phase D)
  char* H1 = lds + 65536;    // T1 panel (phase C)

  const int tid  = threadIdx.x;
  const int w    = tid >> 6;
  const int lane = tid & 63;
  const int lr   = lane & 15;
  const int lq   = lane >> 4;

  const int bid = blockIdx.x;
  const int xcd = bid & 7;
  const int s   = bid >> 3;
  const int b   = xcd * 16 + (s >> 3);
  const int c0  = (s & 7) * NC;

  const unsigned short* CVb = CV + (size_t)b * NV * NV;
  const unsigned short* LRb = LR + (size_t)b * NV * NV;
  const unsigned short* LTb = LT + (size_t)b * NV * NV;
  float*                Ob  = out + (size_t)b * NV * NV;

  f32x4 acc[2][4];

  // ---- load phase-B panel: cholC = LT rows c0..c0+63 -> H0 (source-swizzled)
  #pragma unroll
  for (int cc = 0; cc < 4; ++cc) {
    const int c = cc * 16 + w;
    const unsigned short* src = LTb + (size_t)(c0 + c) * NV + ((lane ^ (c & 7)) * 8);
    gload_lds16(src, H0 + c * 1024);
  }
  asm volatile("s_waitcnt vmcnt(0)" ::: "memory");
  __syncthreads();   // barrier 1: panel visible to all waves

  // ---- Phase B: T1 = CV @ cholC   (A direct from global)
  #pragma unroll
  for (int m = 0; m < 2; ++m)
    #pragma unroll
    for (int n = 0; n < 4; ++n) acc[m][n] = (f32x4)0.f;
  phase_direct(CVb, H0, acc, w, lr, lq);

  // T1 -> H1 (panel format)
  #pragma unroll
  for (int m = 0; m < 2; ++m) {
    #pragma unroll
    for (int n = 0; n < 4; ++n) {
      f32x4 a = acc[m][n];
      u32x2 pk; pk[0] = cvt2(a[0], a[1]); pk[1] = cvt2(a[2], a[3]);
      *(u32x2*)(H1 + swzL(n * 16 + lr, w * 32 + m * 16 + lq * 4)) = pk;
    }
  }
  __syncthreads();   // barrier 2: T1 complete; H0 now dead

  // ---- Phase C: phi = LT-rows @ T1 (masked)   (A direct from global)
  #pragma unroll
  for (int m = 0; m < 2; ++m)
    #pragma unroll
    for (int n = 0; n < 4; ++n) acc[m][n] = (f32x4)0.f;
  phase_direct(LTb, H1, acc, w, lr, lq);

  // mask (strict lower=1, diag=0.5, upper=0); phi -> H0 (dead since barrier 2)
  #pragma unroll
  for (int jt = 0; jt < 2; ++jt) {
    #pragma unroll
    for (int n = 0; n < 4; ++n) {
      f32x4 a = acc[jt][n];
      const int gk = c0 + n * 16 + lr;
      const int j0 = w * 32 + jt * 16 + lq * 4;
      float f[4];
      #pragma unroll
      for (int q = 0; q < 4; ++q) {
        const int j = j0 + q;
        f[q] = (j > gk) ? a[q] : ((j == gk) ? 0.5f * a[q] : 0.f);
      }
      u32x2 pk; pk[0] = cvt2(f[0], f[1]); pk[1] = cvt2(f[2], f[3]);
      *(u32x2*)(H0 + swzL(n * 16 + lr, j0)) = pk;
    }
  }
  __syncthreads();   // barrier 3: phi complete

  // ---- Phase D: out = -LR @ phi   (A direct from global)
  #pragma unroll
  for (int m = 0; m < 2; ++m)
    #pragma unroll
    for (int n = 0; n < 4; ++n) acc[m][n] = (f32x4)0.f;
  phase_direct(LRb, H0, acc, w, lr, lq);

  #pragma unroll
  for (int m = 0; m < 2; ++m) {
    const int i0 = w * 32 + m * 16 + lq * 4;
    #pragma unroll
    for (int n = 0; n < 4; ++n) {
      f32x4 a = acc[m][n];
      const int col = c0 + n * 16 + lr;
      #pragma unroll
      for (int q = 0; q < 4; ++q)
        Ob[(size_t)(i0 + q) * NV + col] = -a[q];
    }
  }
}

// ---------------------------------------------------------------------------
// LT-only fast path (R2 form) for 64MB <= ws < 192MB
// ---------------------------------------------------------------------------
__global__ __launch_bounds__(1024, 1)
void fused_cholTE_fast(const float* __restrict__ covTE,
                       const float* __restrict__ chol,
                       const unsigned short* __restrict__ LT,
                       float* __restrict__ out) {
  __shared__ __align__(16) char lds[131072];
  char* sB0 = lds;
  char* sB1 = lds + 65536;

  const int tid  = threadIdx.x;
  const int w    = tid >> 6;
  const int lane = tid & 63;
  const int lr   = lane & 15;
  const int lq   = lane >> 4;

  const int bid = blockIdx.x;
  const int xcd = bid & 7;
  const int s   = bid >> 3;
  const int b   = xcd * 16 + (s >> 3);
  const int c0  = (s & 7) * NC;

  const float*          Cb  = covTE + (size_t)b * NV * NV;
  const float*          Lb  = chol  + (size_t)b * NV * NV;
  const unsigned short* LTb = LT    + (size_t)b * NV * NV;
  float*                Ob  = out   + (size_t)b * NV * NV;

  #pragma unroll
  for (int cc = 0; cc < 4; ++cc) {
    const int c = cc * 16 + w;
    const unsigned short* src = LTb + (size_t)(c0 + c) * NV + ((lane ^ (c & 7)) * 8);
    gload_lds16(src, sB0 + c * 1024);
  }
  __syncthreads();

  f32x4 acc[2][4];
  #pragma unroll
  for (int m = 0; m < 2; ++m)
    #pragma unroll
    for (int n = 0; n < 4; ++n) acc[m][n] = (f32x4)0.f;

  for (int kb = 0; kb < 16; ++kb) {
    const int kbase = kb * 32 + lq * 8;
    bf8 bfr[4];
    #pragma unroll
    for (int n = 0; n < 4; ++n)
      bfr[n] = *(const bf8*)(sB0 + swzL(n * 16 + lr, kbase));
    #pragma unroll
    for (int m = 0; m < 2; ++m) {
      const float* p = Cb + (size_t)(w * 32 + m * 16 + lr) * NV + kbase;
      fv4 a0 = *(const fv4*)p;
      fv4 a1 = *(const fv4*)(p + 4);
      bf8 af = pack8(a0, a1);
      #pragma unroll
      for (int n = 0; n < 4; ++n)
        acc[m][n] = __builtin_amdgcn_mfma_f32_16x16x32_bf16(af, bfr[n], acc[m][n], 0, 0, 0);
    }
  }
  #pragma unroll
  for (int m = 0; m < 2; ++m) {
    #pragma unroll
    for (int n = 0; n < 4; ++n) {
      f32x4 a = acc[m][n];
      u32x2 pk; pk[0] = cvt2(a[0], a[1]); pk[1] = cvt2(a[2], a[3]);
      *(u32x2*)(sB1 + swzL(n * 16 + lr, w * 32 + m * 16 + lq * 4)) = pk;
    }
  }
  __syncthreads();

  #pragma unroll
  for (int m = 0; m < 2; ++m)
    #pragma unroll
    for (int n = 0; n < 4; ++n) acc[m][n] = (f32x4)0.f;

  for (int ib = 0; ib < 16; ++ib) {
    const int kbase = ib * 32 + lq * 8;
    bf8 bt[4];
    #pragma unroll
    for (int n = 0; n < 4; ++n)
      bt[n] = *(const bf8*)(sB1 + swzL(n * 16 + lr, kbase));
    #pragma unroll
    for (int jt = 0; jt < 2; ++jt) {
      bf8 af = *(const bf8*)(LTb + (size_t)(w * 32 + jt * 16 + lr) * NV + kbase);
      #pragma unroll
      for (int n = 0; n < 4; ++n)
        acc[jt][n] = __builtin_amdgcn_mfma_f32_16x16x32_bf16(af, bt[n], acc[jt][n], 0, 0, 0);
    }
  }
  #pragma unroll
  for (int jt = 0; jt < 2; ++jt) {
    #pragma unroll
    for (int n = 0; n < 4; ++n) {
      f32x4 a = acc[jt][n];
      const int gk = c0 + n * 16 + lr;
      const int j0 = w * 32 + jt * 16 + lq * 4;
      float f[4];
      #pragma unroll
      for (int q = 0; q < 4; ++q) {
        const int j = j0 + q;
        f[q] = (j > gk) ? a[q] : ((j == gk) ? 0.5f * a[q] : 0.f);
      }
      u32x2 pk; pk[0] = cvt2(f[0], f[1]); pk[1] = cvt2(f[2], f[3]);
      *(u32x2*)(sB0 + swzL(n * 16 + lr, j0)) = pk;
    }
  }
  __syncthreads();

  #pragma unroll
  for (int m = 0; m < 2; ++m)
    #pragma unroll
    for (int n = 0; n < 4; ++n) acc[m][n] = (f32x4)0.f;

  for (int kb = 0; kb < 16; ++kb) {
    const int kbase = kb * 32 + lq * 8;
    bf8 bp[4];
    #pragma unroll
    for (int n = 0; n < 4; ++n)
      bp[n] = *(const bf8*)(sB0 + swzL(n * 16 + lr, kbase));
    #pragma unroll
    for (int m = 0; m < 2; ++m) {
      const float* p = Lb + (size_t)(w * 32 + m * 16 + lr) * NV + kbase;
      fv4 a0 = *(const fv4*)p;
      fv4 a1 = *(const fv4*)(p + 4);
      bf8 af = pack8(a0, a1);
      #pragma unroll
      for (int n = 0; n < 4; ++n)
        acc[m][n] = __builtin_amdgcn_mfma_f32_16x16x32_bf16(af, bp[n], acc[m][n], 0, 0, 0);
    }
  }
  #pragma unroll
  for (int m = 0; m < 2; ++m) {
    const int i0 = w * 32 + m * 16 + lq * 4;
    #pragma unroll
    for (int n = 0; n < 4; ++n) {
      f32x4 a = acc[m][n];
      const int col = c0 + n * 16 + lr;
      #pragma unroll
      for (int q = 0; q < 4; ++q)
        Ob[(size_t)(i0 + q) * NV + col] = -a[q];
    }
  }
}

// ---------------------------------------------------------------------------
// No-workspace fallback (R1 form)
// ---------------------------------------------------------------------------
__global__ __launch_bounds__(1024, 1)
void fused_cholTE_fallback(const float* __restrict__ covTE,
                           const float* __restrict__ chol,
                           float* __restrict__ out) {
  __shared__ __align__(16) char lds[131072];
  char* sB0 = lds;
  char* sB1 = lds + 65536;
  char* sCh = lds;

  const int tid  = threadIdx.x;
  const int w    = tid >> 6;
  const int lane = tid & 63;
  const int lr   = lane & 15;
  const int lq   = lane >> 4;

  const int bid = blockIdx.x;
  const int xcd = bid & 7;
  const int s   = bid >> 3;
  const int b   = xcd * 16 + (s >> 3);
  const int c0  = (s & 7) * NC;

  const float* Cb = covTE + (size_t)b * NV * NV;
  const float* Lb = chol  + (size_t)b * NV * NV;
  float*       Ob = out   + (size_t)b * NV * NV;

  {
    const int rr = tid >> 4;
    const int cc = (tid & 15) * 4;
    #pragma unroll
    for (int p = 0; p < 8; ++p) {
      const int r = p * 64 + rr;
      fv4 v = *(const fv4*)(Lb + (size_t)r * NV + c0 + cc);
      *(unsigned short*)(sB0 + swzL(cc + 0, r)) = f2bf(v[0]);
      *(unsigned short*)(sB0 + swzL(cc + 1, r)) = f2bf(v[1]);
      *(unsigned short*)(sB0 + swzL(cc + 2, r)) = f2bf(v[2]);
      *(unsigned short*)(sB0 + swzL(cc + 3, r)) = f2bf(v[3]);
    }
  }
  __syncthreads();

  f32x4 acc[2][4];
  #pragma unroll
  for (int m = 0; m < 2; ++m)
    #pragma unroll
    for (int n = 0; n < 4; ++n) acc[m][n] = (f32x4)0.f;

  for (int kb = 0; kb < 16; ++kb) {
    const int kbase = kb * 32 + lq * 8;
    bf8 bfr[4];
    #pragma unroll
    for (int n = 0; n < 4; ++n)
      bfr[n] = *(const bf8*)(sB0 + swzL(n * 16 + lr, kbase));
    #pragma unroll
    for (int m = 0; m < 2; ++m) {
      const float* p = Cb + (size_t)(w * 32 + m * 16 + lr) * NV + kbase;
      fv4 a0 = *(const fv4*)p;
      fv4 a1 = *(const fv4*)(p + 4);
      bf8 af = pack8(a0, a1);
      #pragma unroll
      for (int n = 0; n < 4; ++n)
        acc[m][n] = __builtin_amdgcn_mfma_f32_16x16x32_bf16(af, bfr[n], acc[m][n], 0, 0, 0);
    }
  }
  #pragma unroll
  for (int m = 0; m < 2; ++m) {
    #pragma unroll
    for (int n = 0; n < 4; ++n) {
      f32x4 a = acc[m][n];
      u32x2 pk; pk[0] = cvt2(a[0], a[1]); pk[1] = cvt2(a[2], a[3]);
      *(u32x2*)(sB1 + swzL(n * 16 + lr, w * 32 + m * 16 + lq * 4)) = pk;
    }
  }
  __syncthreads();

  #pragma unroll
  for (int m = 0; m < 2; ++m)
    #pragma unroll
    for (int n = 0; n < 4; ++n) acc[m][n] = (f32x4)0.f;

  const int sj = (tid & 255) * 2;
  const int so = tid >> 8;

  fv2 raw[8];
  {
    const float* src = Lb + (size_t)(so * 8) * NV + sj;
    #pragma unroll
    for (int r = 0; r < 8; ++r) raw[r] = *(const fv2*)(src + (size_t)r * NV);
    u16x8 p0, p1;
    #pragma unroll
    for (int r = 0; r < 8; ++r) { p0[r] = f2bf(raw[r][0]); p1[r] = f2bf(raw[r][1]); }
    *(u16x8*)(sCh + swzC(sj + 0, so * 8)) = p0;
    *(u16x8*)(sCh + swzC(sj + 1, so * 8)) = p1;
  }
  __syncthreads();

  for (int ib = 0; ib < 16; ++ib) {
    if (ib + 1 < 16) {
      const float* src = Lb + (size_t)((ib + 1) * 32 + so * 8) * NV + sj;
      #pragma unroll
      for (int r = 0; r < 8; ++r) raw[r] = *(const fv2*)(src + (size_t)r * NV);
    }
    bf8 bt[4];
    #pragma unroll
    for (int n = 0; n < 4; ++n)
      bt[n] = *(const bf8*)(sB1 + swzL(n * 16 + lr, ib * 32 + lq * 8));
    #pragma unroll
    for (int jt = 0; jt < 2; ++jt) {
      bf8 af = *(const bf8*)(sCh + swzC(w * 32 + jt * 16 + lr, lq * 8));
      #pragma unroll
      for (int n = 0; n < 4; ++n)
        acc[jt][n] = __builtin_amdgcn_mfma_f32_16x16x32_bf16(af, bt[n], acc[jt][n], 0, 0, 0);
    }
    __syncthreads();
    if (ib + 1 < 16) {
      u16x8 p0, p1;
      #pragma unroll
      for (int r = 0; r < 8; ++r) { p0[r] = f2bf(raw[r][0]); p1[r] = f2bf(raw[r][1]); }
      *(u16x8*)(sCh + swzC(sj + 0, so * 8)) = p0;
      *(u16x8*)(sCh + swzC(sj + 1, so * 8)) = p1;
    }
    __syncthreads();
  }

  #pragma unroll
  for (int jt = 0; jt < 2; ++jt) {
    #pragma unroll
    for (int n = 0; n < 4; ++n) {
      f32x4 a = acc[jt][n];
      const int gk = c0 + n * 16 + lr;
      const int j0 = w * 32 + jt * 16 + lq * 4;
      float f[4];
      #pragma unroll
      for (int q = 0; q < 4; ++q) {
        const int j = j0 + q;
        f[q] = (j > gk) ? a[q] : ((j == gk) ? 0.5f * a[q] : 0.f);
      }
      u32x2 pk; pk[0] = cvt2(f[0], f[1]); pk[1] = cvt2(f[2], f[3]);
      *(u32x2*)(sB0 + swzL(n * 16 + lr, j0)) = pk;
    }
  }
  __syncthreads();

  #pragma unroll
  for (int m = 0; m < 2; ++m)
    #pragma unroll
    for (int n = 0; n < 4; ++n) acc[m][n] = (f32x4)0.f;

  for (int kb = 0; kb < 16; ++kb) {
    const int kbase = kb * 32 + lq * 8;
    bf8 bp[4];
    #pragma unroll
    for (int n = 0; n < 4; ++n)
      bp[n] = *(const bf8*)(sB0 + swzL(n * 16 + lr, kbase));
    #pragma unroll
    for (int m = 0; m < 2; ++m) {
      const float* p = Lb + (size_t)(w * 32 + m * 16 + lr) * NV + kbase;
      fv4 a0 = *(const fv4*)p;
      fv4 a1 = *(const fv4*)(p + 4);
      bf8 af = pack8(a0, a1);
      #pragma unroll
      for (int n = 0; n < 4; ++n)
        acc[m][n] = __builtin_amdgcn_mfma_f32_16x16x32_bf16(af, bp[n], acc[m][n], 0, 0, 0);
    }
  }
  #pragma unroll
  for (int m = 0; m < 2; ++m) {
    const int i0 = w * 32 + m * 16 + lq * 4;
    #pragma unroll
    for (int n = 0; n < 4; ++n) {
      f32x4 a = acc[m][n];
      const int col = c0 + n * 16 + lr;
      #pragma unroll
      for (int q = 0; q < 4; ++q)
        Ob[(size_t)(i0 + q) * NV + col] = -a[q];
    }
  }
}

extern "C" void kernel_launch(void* const* d_in, const int* in_sizes, int n_in,
                              void* d_out, int out_size, void* d_ws, size_t ws_size,
                              hipStream_t stream) {
  const float* muTE  = (const float*)d_in[0];
  const float* covTE = (const float*)d_in[1];
  const float* chol  = (const float*)d_in[2];
  float* out = (float*)d_out;

  (void)hipMemcpyAsync(out, muTE, (size_t)NB * NV * sizeof(float),
                       hipMemcpyDeviceToDevice, stream);

  float* cholTE = out + (size_t)NB * NV;
  const size_t nmat     = (size_t)NB * NV * NV;          // 33,554,432 elems
  const size_t lt_bytes = nmat * sizeof(unsigned short); // 64 MiB

  if (ws_size >= 3 * lt_bytes) {
    unsigned short* CV = (unsigned short*)d_ws;
    unsigned short* LR = CV + nmat;
    unsigned short* LT = LR + nmat;
    conv_f32_bf16_kernel<<<dim3(nmat / (256 * 8)), dim3(256), 0, stream>>>(covTE, CV);
    convert_LT_kernel<<<dim3(NB * 64), dim3(256), 0, stream>>>(chol, LT, LR);
    fused_cholTE_v6<<<dim3(NB * (NV / NC)), dim3(1024), 0, stream>>>(CV, LR, LT, cholTE);
  } else if (ws_size >= lt_bytes) {
    unsigned short* LT = (unsigned short*)d_ws;
    convert_LT_kernel<<<dim3(NB * 64), dim3(256), 0, stream>>>(chol, LT, nullptr);
    fused_cholTE_fast<<<dim3(NB * (NV / NC)), dim3(1024), 0, stream>>>(
        covTE, chol, LT, cholTE);
  } else {
    fused_cholTE_fallback<<<dim3(NB * (NV / NC)), dim3(1024), 0, stream>>>(
        covTE, chol, cholTE);
  }
}

// Round 12
// 305.810 us; speedup vs baseline: 1.5601x; 1.2541x over previous
//
#include <hip/hip_runtime.h>
#include <hip/hip_bf16.h>

#define NV 512
#define NB 128
#define NC 64

typedef float fv4 __attribute__((ext_vector_type(4)));
typedef float fv2 __attribute__((ext_vector_type(2)));
typedef float f32x4 __attribute__((ext_vector_type(4)));
typedef short bf8 __attribute__((ext_vector_type(8)));            // 8 bf16 (MFMA A/B frag)
typedef unsigned short u16x4 __attribute__((ext_vector_type(4)));
typedef unsigned short u16x8 __attribute__((ext_vector_type(8)));
typedef unsigned u32x2 __attribute__((ext_vector_type(2)));
typedef unsigned u32x4 __attribute__((ext_vector_type(4)));

// f32 -> bf16 RNE, scalar
__device__ __forceinline__ unsigned short f2bf(float f) {
  unsigned u = __builtin_bit_cast(unsigned, f);
  u += 0x7fffu + ((u >> 16) & 1u);
  return (unsigned short)(u >> 16);
}

// packed f32x2 -> bf16x2 (v_cvt_pk_bf16_f32)
__device__ __forceinline__ unsigned cvt2(float lo, float hi) {
  __hip_bfloat162 h = __float22bfloat162_rn(make_float2(lo, hi));
  unsigned r;
  __builtin_memcpy(&r, &h, sizeof(r));
  return r;
}

__device__ __forceinline__ bf8 pack8(fv4 a0, fv4 a1) {
  u32x4 r;
  r[0] = cvt2(a0[0], a0[1]);
  r[1] = cvt2(a0[2], a0[3]);
  r[2] = cvt2(a1[0], a1[1]);
  r[3] = cvt2(a1[2], a1[3]);
  return __builtin_bit_cast(bf8, r);
}

// panel: [64 cols][512 rows] bf16, 1KB per col; XOR swizzle on 16B granules
__device__ __forceinline__ int swzL(int c, int r) {
  return ((c << 10) + (r << 1)) ^ ((c & 7) << 4);
}
// fallback staging layout
__device__ __forceinline__ int swzC(int j, int ii) {
  return ((j << 6) + (ii << 1)) ^ ((j & 3) << 4);
}

__device__ __forceinline__ void gload_lds16(const void* g, void* l) {
  __builtin_amdgcn_global_load_lds(
      (const __attribute__((address_space(1))) unsigned int*)g,
      (__attribute__((address_space(3))) unsigned int*)l, 16, 0, 0);
}

// ---------------------------------------------------------------------------
// Convert kernels
// ---------------------------------------------------------------------------
__global__ __launch_bounds__(256, 4)
void conv_f32_bf16_kernel(const float* __restrict__ src, unsigned short* __restrict__ dst) {
  const size_t i8 = ((size_t)blockIdx.x * 256 + threadIdx.x) * 8;
  fv4 a0 = *(const fv4*)(src + i8);
  fv4 a1 = *(const fv4*)(src + i8 + 4);
  u32x4 r;
  r[0] = cvt2(a0[0], a0[1]); r[1] = cvt2(a0[2], a0[3]);
  r[2] = cvt2(a1[0], a1[1]); r[3] = cvt2(a1[2], a1[3]);
  *(u32x4*)(dst + i8) = r;
}

// chol f32 -> LR bf16 (row-major, optional) + LT bf16 (transposed)
__global__ __launch_bounds__(256, 4)
void convert_LT_kernel(const float* __restrict__ chol,
                       unsigned short* __restrict__ LT,
                       unsigned short* __restrict__ LR) {
  __shared__ unsigned short T[64][72];
  const int bid = blockIdx.x;
  const int b  = bid >> 6;
  const int t  = bid & 63;
  const int ti = t >> 3, tj = t & 7;

  const float* src = chol + ((size_t)b * NV + ti * 64) * NV + tj * 64;
  {
    const int r0 = threadIdx.x >> 4;
    const int c4 = (threadIdx.x & 15) * 4;
    #pragma unroll
    for (int p = 0; p < 4; ++p) {
      const int r = p * 16 + r0;
      fv4 v = *(const fv4*)(src + (size_t)r * NV + c4);
      T[c4 + 0][r] = f2bf(v[0]);
      T[c4 + 1][r] = f2bf(v[1]);
      T[c4 + 2][r] = f2bf(v[2]);
      T[c4 + 3][r] = f2bf(v[3]);
      if (LR) {
        u32x2 pk; pk[0] = cvt2(v[0], v[1]); pk[1] = cvt2(v[2], v[3]);
        *(u32x2*)(LR + ((size_t)b * NV + ti * 64 + r) * NV + tj * 64 + c4) = pk;
      }
    }
  }
  __syncthreads();
  unsigned short* dst = LT + ((size_t)b * NV + tj * 64) * NV + ti * 64;
  const int c  = threadIdx.x >> 2;
  const int k8 = (threadIdx.x & 3) * 16;
  u16x8 o0, o1;
  #pragma unroll
  for (int q = 0; q < 8; ++q) { o0[q] = T[c][k8 + q]; o1[q] = T[c][k8 + 8 + q]; }
  *(u16x8*)(dst + (size_t)c * NV + k8)     = o0;
  *(u16x8*)(dst + (size_t)c * NV + k8 + 8) = o1;
}

// ---------------------------------------------------------------------------
// v7 main kernel: 512 threads (8 waves), M=64 rows/wave (acc[4][4]),
// SINGLE 64KB panel (cholC -> T1 -> phi in place, 5 barriers),
// A direct from global bf16, 2 WGs/CU via __launch_bounds__(512,4).
// ---------------------------------------------------------------------------
__device__ __forceinline__ void phase_v7(const unsigned short* Abase,
                                         const char* panel,
                                         f32x4 (&acc)[4][4],
                                         int w, int lr, int lq) {
  const unsigned short* rA = Abase + (size_t)(w * 64 + lr) * NV + lq * 8;
  #pragma unroll 2
  for (int t = 0; t < 16; ++t) {
    const int kbase = t * 32 + lq * 8;
    bf8 a[4];
    #pragma unroll
    for (int m = 0; m < 4; ++m)
      a[m] = *(const bf8*)(rA + (size_t)(m * 16) * NV + t * 32);
    bf8 bfr[4];
    #pragma unroll
    for (int n = 0; n < 4; ++n)
      bfr[n] = *(const bf8*)(panel + swzL(n * 16 + lr, kbase));
    #pragma unroll
    for (int m = 0; m < 4; ++m)
      #pragma unroll
      for (int n = 0; n < 4; ++n)
        acc[m][n] = __builtin_amdgcn_mfma_f32_16x16x32_bf16(a[m], bfr[n], acc[m][n], 0, 0, 0);
  }
}

__global__ __launch_bounds__(512, 4)
void fused_cholTE_v7(const unsigned short* __restrict__ CV,
                     const unsigned short* __restrict__ LR,
                     const unsigned short* __restrict__ LT,
                     float* __restrict__ out) {
  __shared__ __align__(16) char H[65536];   // one panel: cholC -> T1 -> phi

  const int tid  = threadIdx.x;
  const int w    = tid >> 6;     // wave 0..7
  const int lane = tid & 63;
  const int lr   = lane & 15;
  const int lq   = lane >> 4;

  const int bid = blockIdx.x;
  const int xcd = bid & 7;
  const int s   = bid >> 3;
  const int b   = xcd * 16 + (s >> 3);
  const int c0  = (s & 7) * NC;

  const unsigned short* CVb = CV + (size_t)b * NV * NV;
  const unsigned short* LRb = LR + (size_t)b * NV * NV;
  const unsigned short* LTb = LT + (size_t)b * NV * NV;
  float*                Ob  = out + (size_t)b * NV * NV;

  f32x4 acc[4][4];

  // ---- stage phase-B panel: cholC = LT rows c0..c0+63 -> H (source-swizzled)
  #pragma unroll
  for (int cc = 0; cc < 8; ++cc) {
    const int c = cc * 8 + w;
    const unsigned short* src = LTb + (size_t)(c0 + c) * NV + ((lane ^ (c & 7)) * 8);
    gload_lds16(src, H + c * 1024);
  }
  asm volatile("s_waitcnt vmcnt(0)" ::: "memory");
  __syncthreads();   // barrier 1: cholC panel ready

  // ---- Phase B: T1 = CV @ cholC
  #pragma unroll
  for (int m = 0; m < 4; ++m)
    #pragma unroll
    for (int n = 0; n < 4; ++n) acc[m][n] = (f32x4)0.f;
  phase_v7(CVb, H, acc, w, lr, lq);
  __syncthreads();   // barrier 2: all waves done reading cholC

  // T1 -> H (overwrite cholC)
  #pragma unroll
  for (int m = 0; m < 4; ++m) {
    #pragma unroll
    for (int n = 0; n < 4; ++n) {
      f32x4 a = acc[m][n];
      u32x2 pk; pk[0] = cvt2(a[0], a[1]); pk[1] = cvt2(a[2], a[3]);
      *(u32x2*)(H + swzL(n * 16 + lr, w * 64 + m * 16 + lq * 4)) = pk;
    }
  }
  __syncthreads();   // barrier 3: T1 panel ready

  // ---- Phase C: phi = LT-rows @ T1 (masked)
  #pragma unroll
  for (int m = 0; m < 4; ++m)
    #pragma unroll
    for (int n = 0; n < 4; ++n) acc[m][n] = (f32x4)0.f;
  phase_v7(LTb, H, acc, w, lr, lq);
  __syncthreads();   // barrier 4: all waves done reading T1

  // mask (strict lower=1, diag=0.5, upper=0); phi -> H (overwrite T1)
  #pragma unroll
  for (int jt = 0; jt < 4; ++jt) {
    #pragma unroll
    for (int n = 0; n < 4; ++n) {
      f32x4 a = acc[jt][n];
      const int gk = c0 + n * 16 + lr;
      const int j0 = w * 64 + jt * 16 + lq * 4;
      float f[4];
      #pragma unroll
      for (int q = 0; q < 4; ++q) {
        const int j = j0 + q;
        f[q] = (j > gk) ? a[q] : ((j == gk) ? 0.5f * a[q] : 0.f);
      }
      u32x2 pk; pk[0] = cvt2(f[0], f[1]); pk[1] = cvt2(f[2], f[3]);
      *(u32x2*)(H + swzL(n * 16 + lr, j0)) = pk;
    }
  }
  __syncthreads();   // barrier 5: phi panel ready

  // ---- Phase D: out = -LR @ phi
  #pragma unroll
  for (int m = 0; m < 4; ++m)
    #pragma unroll
    for (int n = 0; n < 4; ++n) acc[m][n] = (f32x4)0.f;
  phase_v7(LRb, H, acc, w, lr, lq);

  #pragma unroll
  for (int m = 0; m < 4; ++m) {
    const int i0 = w * 64 + m * 16 + lq * 4;
    #pragma unroll
    for (int n = 0; n < 4; ++n) {
      f32x4 a = acc[m][n];
      const int col = c0 + n * 16 + lr;
      #pragma unroll
      for (int q = 0; q < 4; ++q)
        Ob[(size_t)(i0 + q) * NV + col] = -a[q];
    }
  }
}

// ---------------------------------------------------------------------------
// LT-only fast path (R2 form) for 64MB <= ws < 192MB
// ---------------------------------------------------------------------------
__global__ __launch_bounds__(1024, 1)
void fused_cholTE_fast(const float* __restrict__ covTE,
                       const float* __restrict__ chol,
                       const unsigned short* __restrict__ LT,
                       float* __restrict__ out) {
  __shared__ __align__(16) char lds[131072];
  char* sB0 = lds;
  char* sB1 = lds + 65536;

  const int tid  = threadIdx.x;
  const int w    = tid >> 6;
  const int lane = tid & 63;
  const int lr   = lane & 15;
  const int lq   = lane >> 4;

  const int bid = blockIdx.x;
  const int xcd = bid & 7;
  const int s   = bid >> 3;
  const int b   = xcd * 16 + (s >> 3);
  const int c0  = (s & 7) * NC;

  const float*          Cb  = covTE + (size_t)b * NV * NV;
  const float*          Lb  = chol  + (size_t)b * NV * NV;
  const unsigned short* LTb = LT    + (size_t)b * NV * NV;
  float*                Ob  = out   + (size_t)b * NV * NV;

  #pragma unroll
  for (int cc = 0; cc < 4; ++cc) {
    const int c = cc * 16 + w;
    const unsigned short* src = LTb + (size_t)(c0 + c) * NV + ((lane ^ (c & 7)) * 8);
    gload_lds16(src, sB0 + c * 1024);
  }
  __syncthreads();

  f32x4 acc[2][4];
  #pragma unroll
  for (int m = 0; m < 2; ++m)
    #pragma unroll
    for (int n = 0; n < 4; ++n) acc[m][n] = (f32x4)0.f;

  for (int kb = 0; kb < 16; ++kb) {
    const int kbase = kb * 32 + lq * 8;
    bf8 bfr[4];
    #pragma unroll
    for (int n = 0; n < 4; ++n)
      bfr[n] = *(const bf8*)(sB0 + swzL(n * 16 + lr, kbase));
    #pragma unroll
    for (int m = 0; m < 2; ++m) {
      const float* p = Cb + (size_t)(w * 32 + m * 16 + lr) * NV + kbase;
      fv4 a0 = *(const fv4*)p;
      fv4 a1 = *(const fv4*)(p + 4);
      bf8 af = pack8(a0, a1);
      #pragma unroll
      for (int n = 0; n < 4; ++n)
        acc[m][n] = __builtin_amdgcn_mfma_f32_16x16x32_bf16(af, bfr[n], acc[m][n], 0, 0, 0);
    }
  }
  #pragma unroll
  for (int m = 0; m < 2; ++m) {
    #pragma unroll
    for (int n = 0; n < 4; ++n) {
      f32x4 a = acc[m][n];
      u32x2 pk; pk[0] = cvt2(a[0], a[1]); pk[1] = cvt2(a[2], a[3]);
      *(u32x2*)(sB1 + swzL(n * 16 + lr, w * 32 + m * 16 + lq * 4)) = pk;
    }
  }
  __syncthreads();

  #pragma unroll
  for (int m = 0; m < 2; ++m)
    #pragma unroll
    for (int n = 0; n < 4; ++n) acc[m][n] = (f32x4)0.f;

  for (int ib = 0; ib < 16; ++ib) {
    const int kbase = ib * 32 + lq * 8;
    bf8 bt[4];
    #pragma unroll
    for (int n = 0; n < 4; ++n)
      bt[n] = *(const bf8*)(sB1 + swzL(n * 16 + lr, kbase));
    #pragma unroll
    for (int jt = 0; jt < 2; ++jt) {
      bf8 af = *(const bf8*)(LTb + (size_t)(w * 32 + jt * 16 + lr) * NV + kbase);
      #pragma unroll
      for (int n = 0; n < 4; ++n)
        acc[jt][n] = __builtin_amdgcn_mfma_f32_16x16x32_bf16(af, bt[n], acc[jt][n], 0, 0, 0);
    }
  }
  #pragma unroll
  for (int jt = 0; jt < 2; ++jt) {
    #pragma unroll
    for (int n = 0; n < 4; ++n) {
      f32x4 a = acc[jt][n];
      const int gk = c0 + n * 16 + lr;
      const int j0 = w * 32 + jt * 16 + lq * 4;
      float f[4];
      #pragma unroll
      for (int q = 0; q < 4; ++q) {
        const int j = j0 + q;
        f[q] = (j > gk) ? a[q] : ((j == gk) ? 0.5f * a[q] : 0.f);
      }
      u32x2 pk; pk[0] = cvt2(f[0], f[1]); pk[1] = cvt2(f[2], f[3]);
      *(u32x2*)(sB0 + swzL(n * 16 + lr, j0)) = pk;
    }
  }
  __syncthreads();

  #pragma unroll
  for (int m = 0; m < 2; ++m)
    #pragma unroll
    for (int n = 0; n < 4; ++n) acc[m][n] = (f32x4)0.f;

  for (int kb = 0; kb < 16; ++kb) {
    const int kbase = kb * 32 + lq * 8;
    bf8 bp[4];
    #pragma unroll
    for (int n = 0; n < 4; ++n)
      bp[n] = *(const bf8*)(sB0 + swzL(n * 16 + lr, kbase));
    #pragma unroll
    for (int m = 0; m < 2; ++m) {
      const float* p = Lb + (size_t)(w * 32 + m * 16 + lr) * NV + kbase;
      fv4 a0 = *(const fv4*)p;
      fv4 a1 = *(const fv4*)(p + 4);
      bf8 af = pack8(a0, a1);
      #pragma unroll
      for (int n = 0; n < 4; ++n)
        acc[m][n] = __builtin_amdgcn_mfma_f32_16x16x32_bf16(af, bp[n], acc[m][n], 0, 0, 0);
    }
  }
  #pragma unroll
  for (int m = 0; m < 2; ++m) {
    const int i0 = w * 32 + m * 16 + lq * 4;
    #pragma unroll
    for (int n = 0; n < 4; ++n) {
      f32x4 a = acc[m][n];
      const int col = c0 + n * 16 + lr;
      #pragma unroll
      for (int q = 0; q < 4; ++q)
        Ob[(size_t)(i0 + q) * NV + col] = -a[q];
    }
  }
}

// ---------------------------------------------------------------------------
// No-workspace fallback (R1 form)
// ---------------------------------------------------------------------------
__global__ __launch_bounds__(1024, 1)
void fused_cholTE_fallback(const float* __restrict__ covTE,
                           const float* __restrict__ chol,
                           float* __restrict__ out) {
  __shared__ __align__(16) char lds[131072];
  char* sB0 = lds;
  char* sB1 = lds + 65536;
  char* sCh = lds;

  const int tid  = threadIdx.x;
  const int w    = tid >> 6;
  const int lane = tid & 63;
  const int lr   = lane & 15;
  const int lq   = lane >> 4;

  const int bid = blockIdx.x;
  const int xcd = bid & 7;
  const int s   = bid >> 3;
  const int b   = xcd * 16 + (s >> 3);
  const int c0  = (s & 7) * NC;

  const float* Cb = covTE + (size_t)b * NV * NV;
  const float* Lb = chol  + (size_t)b * NV * NV;
  float*       Ob = out   + (size_t)b * NV * NV;

  {
    const int rr = tid >> 4;
    const int cc = (tid & 15) * 4;
    #pragma unroll
    for (int p = 0; p < 8; ++p) {
      const int r = p * 64 + rr;
      fv4 v = *(const fv4*)(Lb + (size_t)r * NV + c0 + cc);
      *(unsigned short*)(sB0 + swzL(cc + 0, r)) = f2bf(v[0]);
      *(unsigned short*)(sB0 + swzL(cc + 1, r)) = f2bf(v[1]);
      *(unsigned short*)(sB0 + swzL(cc + 2, r)) = f2bf(v[2]);
      *(unsigned short*)(sB0 + swzL(cc + 3, r)) = f2bf(v[3]);
    }
  }
  __syncthreads();

  f32x4 acc[2][4];
  #pragma unroll
  for (int m = 0; m < 2; ++m)
    #pragma unroll
    for (int n = 0; n < 4; ++n) acc[m][n] = (f32x4)0.f;

  for (int kb = 0; kb < 16; ++kb) {
    const int kbase = kb * 32 + lq * 8;
    bf8 bfr[4];
    #pragma unroll
    for (int n = 0; n < 4; ++n)
      bfr[n] = *(const bf8*)(sB0 + swzL(n * 16 + lr, kbase));
    #pragma unroll
    for (int m = 0; m < 2; ++m) {
      const float* p = Cb + (size_t)(w * 32 + m * 16 + lr) * NV + kbase;
      fv4 a0 = *(const fv4*)p;
      fv4 a1 = *(const fv4*)(p + 4);
      bf8 af = pack8(a0, a1);
      #pragma unroll
      for (int n = 0; n < 4; ++n)
        acc[m][n] = __builtin_amdgcn_mfma_f32_16x16x32_bf16(af, bfr[n], acc[m][n], 0, 0, 0);
    }
  }
  #pragma unroll
  for (int m = 0; m < 2; ++m) {
    #pragma unroll
    for (int n = 0; n < 4; ++n) {
      f32x4 a = acc[m][n];
      u32x2 pk; pk[0] = cvt2(a[0], a[1]); pk[1] = cvt2(a[2], a[3]);
      *(u32x2*)(sB1 + swzL(n * 16 + lr, w * 32 + m * 16 + lq * 4)) = pk;
    }
  }
  __syncthreads();

  #pragma unroll
  for (int m = 0; m < 2; ++m)
    #pragma unroll
    for (int n = 0; n < 4; ++n) acc[m][n] = (f32x4)0.f;

  const int sj = (tid & 255) * 2;
  const int so = tid >> 8;

  fv2 raw[8];
  {
    const float* src = Lb + (size_t)(so * 8) * NV + sj;
    #pragma unroll
    for (int r = 0; r < 8; ++r) raw[r] = *(const fv2*)(src + (size_t)r * NV);
    u16x8 p0, p1;
    #pragma unroll
    for (int r = 0; r < 8; ++r) { p0[r] = f2bf(raw[r][0]); p1[r] = f2bf(raw[r][1]); }
    *(u16x8*)(sCh + swzC(sj + 0, so * 8)) = p0;
    *(u16x8*)(sCh + swzC(sj + 1, so * 8)) = p1;
  }
  __syncthreads();

  for (int ib = 0; ib < 16; ++ib) {
    if (ib + 1 < 16) {
      const float* src = Lb + (size_t)((ib + 1) * 32 + so * 8) * NV + sj;
      #pragma unroll
      for (int r = 0; r < 8; ++r) raw[r] = *(const fv2*)(src + (size_t)r * NV);
    }
    bf8 bt[4];
    #pragma unroll
    for (int n = 0; n < 4; ++n)
      bt[n] = *(const bf8*)(sB1 + swzL(n * 16 + lr, ib * 32 + lq * 8));
    #pragma unroll
    for (int jt = 0; jt < 2; ++jt) {
      bf8 af = *(const bf8*)(sCh + swzC(w * 32 + jt * 16 + lr, lq * 8));
      #pragma unroll
      for (int n = 0; n < 4; ++n)
        acc[jt][n] = __builtin_amdgcn_mfma_f32_16x16x32_bf16(af, bt[n], acc[jt][n], 0, 0, 0);
    }
    __syncthreads();
    if (ib + 1 < 16) {
      u16x8 p0, p1;
      #pragma unroll
      for (int r = 0; r < 8; ++r) { p0[r] = f2bf(raw[r][0]); p1[r] = f2bf(raw[r][1]); }
      *(u16x8*)(sCh + swzC(sj + 0, so * 8)) = p0;
      *(u16x8*)(sCh + swzC(sj + 1, so * 8)) = p1;
    }
    __syncthreads();
  }

  #pragma unroll
  for (int jt = 0; jt < 2; ++jt) {
    #pragma unroll
    for (int n = 0; n < 4; ++n) {
      f32x4 a = acc[jt][n];
      const int gk = c0 + n * 16 + lr;
      const int j0 = w * 32 + jt * 16 + lq * 4;
      float f[4];
      #pragma unroll
      for (int q = 0; q < 4; ++q) {
        const int j = j0 + q;
        f[q] = (j > gk) ? a[q] : ((j == gk) ? 0.5f * a[q] : 0.f);
      }
      u32x2 pk; pk[0] = cvt2(f[0], f[1]); pk[1] = cvt2(f[2], f[3]);
      *(u32x2*)(sB0 + swzL(n * 16 + lr, j0)) = pk;
    }
  }
  __syncthreads();

  #pragma unroll
  for (int m = 0; m < 2; ++m)
    #pragma unroll
    for (int n = 0; n < 4; ++n) acc[m][n] = (f32x4)0.f;

  for (int kb = 0; kb < 16; ++kb) {
    const int kbase = kb * 32 + lq * 8;
    bf8 bp[4];
    #pragma unroll
    for (int n = 0; n < 4; ++n)
      bp[n] = *(const bf8*)(sB0 + swzL(n * 16 + lr, kbase));
    #pragma unroll
    for (int m = 0; m < 2; ++m) {
      const float* p = Lb + (size_t)(w * 32 + m * 16 + lr) * NV + kbase;
      fv4 a0 = *(const fv4*)p;
      fv4 a1 = *(const fv4*)(p + 4);
      bf8 af = pack8(a0, a1);
      #pragma unroll
      for (int n = 0; n < 4; ++n)
        acc[m][n] = __builtin_amdgcn_mfma_f32_16x16x32_bf16(af, bp[n], acc[m][n], 0, 0, 0);
    }
  }
  #pragma unroll
  for (int m = 0; m < 2; ++m) {
    const int i0 = w * 32 + m * 16 + lq * 4;
    #pragma unroll
    for (int n = 0; n < 4; ++n) {
      f32x4 a = acc[m][n];
      const int col = c0 + n * 16 + lr;
      #pragma unroll
      for (int q = 0; q < 4; ++q)
        Ob[(size_t)(i0 + q) * NV + col] = -a[q];
    }
  }
}

extern "C" void kernel_launch(void* const* d_in, const int* in_sizes, int n_in,
                              void* d_out, int out_size, void* d_ws, size_t ws_size,
                              hipStream_t stream) {
  const float* muTE  = (const float*)d_in[0];
  const float* covTE = (const float*)d_in[1];
  const float* chol  = (const float*)d_in[2];
  float* out = (float*)d_out;

  (void)hipMemcpyAsync(out, muTE, (size_t)NB * NV * sizeof(float),
                       hipMemcpyDeviceToDevice, stream);

  float* cholTE = out + (size_t)NB * NV;
  const size_t nmat     = (size_t)NB * NV * NV;          // 33,554,432 elems
  const size_t lt_bytes = nmat * sizeof(unsigned short); // 64 MiB

  if (ws_size >= 3 * lt_bytes) {
    unsigned short* CV = (unsigned short*)d_ws;
    unsigned short* LR = CV + nmat;
    unsigned short* LT = LR + nmat;
    conv_f32_bf16_kernel<<<dim3(nmat / (256 * 8)), dim3(256), 0, stream>>>(covTE, CV);
    convert_LT_kernel<<<dim3(NB * 64), dim3(256), 0, stream>>>(chol, LT, LR);
    fused_cholTE_v7<<<dim3(NB * (NV / NC)), dim3(512), 0, stream>>>(CV, LR, LT, cholTE);
  } else if (ws_size >= lt_bytes) {
    unsigned short* LT = (unsigned short*)d_ws;
    convert_LT_kernel<<<dim3(NB * 64), dim3(256), 0, stream>>>(chol, LT, nullptr);
    fused_cholTE_fast<<<dim3(NB * (NV / NC)), dim3(1024), 0, stream>>>(
        covTE, chol, LT, cholTE);
  } else {
    fused_cholTE_fallback<<<dim3(NB * (NV / NC)), dim3(1024), 0, stream>>>(
        covTE, chol, cholTE);
  }
}

// Round 13
// 240.493 us; speedup vs baseline: 1.9838x; 1.2716x over previous
//
#include <hip/hip_runtime.h>
#include <hip/hip_bf16.h>

#define NV 512
#define NB 128
#define NC 64

typedef float fv4 __attribute__((ext_vector_type(4)));
typedef float fv2 __attribute__((ext_vector_type(2)));
typedef float f32x4 __attribute__((ext_vector_type(4)));
typedef short bf8 __attribute__((ext_vector_type(8)));            // 8 bf16 (MFMA A/B frag)
typedef unsigned short u16x4 __attribute__((ext_vector_type(4)));
typedef unsigned short u16x8 __attribute__((ext_vector_type(8)));
typedef unsigned u32x2 __attribute__((ext_vector_type(2)));
typedef unsigned u32x4 __attribute__((ext_vector_type(4)));

// f32 -> bf16 RNE, scalar
__device__ __forceinline__ unsigned short f2bf(float f) {
  unsigned u = __builtin_bit_cast(unsigned, f);
  u += 0x7fffu + ((u >> 16) & 1u);
  return (unsigned short)(u >> 16);
}

// packed f32x2 -> bf16x2 (v_cvt_pk_bf16_f32)
__device__ __forceinline__ unsigned cvt2(float lo, float hi) {
  __hip_bfloat162 h = __float22bfloat162_rn(make_float2(lo, hi));
  unsigned r;
  __builtin_memcpy(&r, &h, sizeof(r));
  return r;
}

__device__ __forceinline__ bf8 pack8(fv4 a0, fv4 a1) {
  u32x4 r;
  r[0] = cvt2(a0[0], a0[1]);
  r[1] = cvt2(a0[2], a0[3]);
  r[2] = cvt2(a1[0], a1[1]);
  r[3] = cvt2(a1[2], a1[3]);
  return __builtin_bit_cast(bf8, r);
}

// panel: [cols][512 rows] bf16, 1KB per col; XOR swizzle on 16B granules
__device__ __forceinline__ int swzL(int c, int r) {
  return ((c << 10) + (r << 1)) ^ ((c & 7) << 4);
}
// fallback staging layout
__device__ __forceinline__ int swzC(int j, int ii) {
  return ((j << 6) + (ii << 1)) ^ ((j & 3) << 4);
}

__device__ __forceinline__ void gload_lds16(const void* g, void* l) {
  __builtin_amdgcn_global_load_lds(
      (const __attribute__((address_space(1))) unsigned int*)g,
      (__attribute__((address_space(3))) unsigned int*)l, 16, 0, 0);
}

// ---------------------------------------------------------------------------
// Convert kernels
// ---------------------------------------------------------------------------
__global__ __launch_bounds__(256, 4)
void conv_f32_bf16_kernel(const float* __restrict__ src, unsigned short* __restrict__ dst) {
  const size_t i8 = ((size_t)blockIdx.x * 256 + threadIdx.x) * 8;
  fv4 a0 = *(const fv4*)(src + i8);
  fv4 a1 = *(const fv4*)(src + i8 + 4);
  u32x4 r;
  r[0] = cvt2(a0[0], a0[1]); r[1] = cvt2(a0[2], a0[3]);
  r[2] = cvt2(a1[0], a1[1]); r[3] = cvt2(a1[2], a1[3]);
  *(u32x4*)(dst + i8) = r;
}

// chol f32 -> LR bf16 (row-major, optional) + LT bf16 (transposed)
__global__ __launch_bounds__(256, 4)
void convert_LT_kernel(const float* __restrict__ chol,
                       unsigned short* __restrict__ LT,
                       unsigned short* __restrict__ LR) {
  __shared__ unsigned short T[64][72];
  const int bid = blockIdx.x;
  const int b  = bid >> 6;
  const int t  = bid & 63;
  const int ti = t >> 3, tj = t & 7;

  const float* src = chol + ((size_t)b * NV + ti * 64) * NV + tj * 64;
  {
    const int r0 = threadIdx.x >> 4;
    const int c4 = (threadIdx.x & 15) * 4;
    #pragma unroll
    for (int p = 0; p < 4; ++p) {
      const int r = p * 16 + r0;
      fv4 v = *(const fv4*)(src + (size_t)r * NV + c4);
      T[c4 + 0][r] = f2bf(v[0]);
      T[c4 + 1][r] = f2bf(v[1]);
      T[c4 + 2][r] = f2bf(v[2]);
      T[c4 + 3][r] = f2bf(v[3]);
      if (LR) {
        u32x2 pk; pk[0] = cvt2(v[0], v[1]); pk[1] = cvt2(v[2], v[3]);
        *(u32x2*)(LR + ((size_t)b * NV + ti * 64 + r) * NV + tj * 64 + c4) = pk;
      }
    }
  }
  __syncthreads();
  unsigned short* dst = LT + ((size_t)b * NV + tj * 64) * NV + ti * 64;
  const int c  = threadIdx.x >> 2;
  const int k8 = (threadIdx.x & 3) * 16;
  u16x8 o0, o1;
  #pragma unroll
  for (int q = 0; q < 8; ++q) { o0[q] = T[c][k8 + q]; o1[q] = T[c][k8 + 8 + q]; }
  *(u16x8*)(dst + (size_t)c * NV + k8)     = o0;
  *(u16x8*)(dst + (size_t)c * NV + k8 + 8) = o1;
}

// ---------------------------------------------------------------------------
// v8 main kernel: 512 threads, 2 waves/SIMD (1 WG/CU, 256-reg budget),
// TWO 64-col panels per WG (128KB LDS). Each K-iter: A-frags loaded ONCE,
// feed 32 MFMA (two acc blocks). A-traffic halves; compute density doubles.
// ---------------------------------------------------------------------------
__device__ __forceinline__ void phase_v8(const unsigned short* Abase,
                                         const char* H,
                                         f32x4 (&acc0)[4][4], f32x4 (&acc1)[4][4],
                                         int w, int lr, int lq) {
  const unsigned short* rA = Abase + (size_t)(w * 64 + lr) * NV + lq * 8;
  #pragma unroll 2
  for (int t = 0; t < 16; ++t) {
    const int kbase = t * 32 + lq * 8;
    bf8 a[4];
    #pragma unroll
    for (int m = 0; m < 4; ++m)
      a[m] = *(const bf8*)(rA + (size_t)(m * 16) * NV + t * 32);
    bf8 b0[4];
    #pragma unroll
    for (int n = 0; n < 4; ++n)
      b0[n] = *(const bf8*)(H + swzL(n * 16 + lr, kbase));
    #pragma unroll
    for (int m = 0; m < 4; ++m)
      #pragma unroll
      for (int n = 0; n < 4; ++n)
        acc0[m][n] = __builtin_amdgcn_mfma_f32_16x16x32_bf16(a[m], b0[n], acc0[m][n], 0, 0, 0);
    bf8 b1[4];
    #pragma unroll
    for (int n = 0; n < 4; ++n)
      b1[n] = *(const bf8*)(H + swzL(64 + n * 16 + lr, kbase));
    #pragma unroll
    for (int m = 0; m < 4; ++m)
      #pragma unroll
      for (int n = 0; n < 4; ++n)
        acc1[m][n] = __builtin_amdgcn_mfma_f32_16x16x32_bf16(a[m], b1[n], acc1[m][n], 0, 0, 0);
  }
}

__global__ __launch_bounds__(512, 2)
void fused_cholTE_v8(const unsigned short* __restrict__ CV,
                     const unsigned short* __restrict__ LR,
                     const unsigned short* __restrict__ LT,
                     float* __restrict__ out) {
  __shared__ __align__(16) char H[131072];   // 128 cols x 1KB: cholC -> T1 -> phi

  const int tid  = threadIdx.x;
  const int w    = tid >> 6;     // wave 0..7
  const int lane = tid & 63;
  const int lr   = lane & 15;
  const int lq   = lane >> 4;

  // 512 WGs: xcd = bid%8; per XCD 16 batches x 4 col-pairs, batch-major
  const int bid = blockIdx.x;
  const int xcd = bid & 7;
  const int s   = bid >> 3;            // 0..63
  const int b   = xcd * 16 + (s >> 2); // batch
  const int c0  = (s & 3) * 128;       // column pair base (two 64-col panels)

  const unsigned short* CVb = CV + (size_t)b * NV * NV;
  const unsigned short* LRb = LR + (size_t)b * NV * NV;
  const unsigned short* LTb = LT + (size_t)b * NV * NV;
  float*                Ob  = out + (size_t)b * NV * NV;

  f32x4 acc0[4][4], acc1[4][4];

  // ---- stage both cholC panels: LT rows c0..c0+127 -> H (source-swizzled)
  #pragma unroll
  for (int cc = 0; cc < 16; ++cc) {
    const int c = cc * 8 + w;
    const unsigned short* src = LTb + (size_t)(c0 + c) * NV + ((lane ^ (c & 7)) * 8);
    gload_lds16(src, H + c * 1024);
  }
  asm volatile("s_waitcnt vmcnt(0)" ::: "memory");
  __syncthreads();   // barrier 1: cholC panels ready

  // ---- Phase B: T1 = CV @ cholC (both panels)
  #pragma unroll
  for (int m = 0; m < 4; ++m)
    #pragma unroll
    for (int n = 0; n < 4; ++n) { acc0[m][n] = (f32x4)0.f; acc1[m][n] = (f32x4)0.f; }
  phase_v8(CVb, H, acc0, acc1, w, lr, lq);
  __syncthreads();   // barrier 2: done reading cholC

  // T1 -> H (overwrite)
  #pragma unroll
  for (int m = 0; m < 4; ++m) {
    #pragma unroll
    for (int n = 0; n < 4; ++n) {
      const int rrow = w * 64 + m * 16 + lq * 4;
      f32x4 a = acc0[m][n];
      u32x2 pk; pk[0] = cvt2(a[0], a[1]); pk[1] = cvt2(a[2], a[3]);
      *(u32x2*)(H + swzL(n * 16 + lr, rrow)) = pk;
      a = acc1[m][n];
      pk[0] = cvt2(a[0], a[1]); pk[1] = cvt2(a[2], a[3]);
      *(u32x2*)(H + swzL(64 + n * 16 + lr, rrow)) = pk;
    }
  }
  __syncthreads();   // barrier 3: T1 panels ready

  // ---- Phase C: phi = LT-rows @ T1 (masked)
  #pragma unroll
  for (int m = 0; m < 4; ++m)
    #pragma unroll
    for (int n = 0; n < 4; ++n) { acc0[m][n] = (f32x4)0.f; acc1[m][n] = (f32x4)0.f; }
  phase_v8(LTb, H, acc0, acc1, w, lr, lq);
  __syncthreads();   // barrier 4: done reading T1

  // mask (strict lower=1, diag=0.5, upper=0); phi -> H (overwrite)
  #pragma unroll
  for (int jt = 0; jt < 4; ++jt) {
    #pragma unroll
    for (int n = 0; n < 4; ++n) {
      const int j0 = w * 64 + jt * 16 + lq * 4;
      const int gk0 = c0 + n * 16 + lr;
      const int gk1 = gk0 + 64;
      f32x4 a = acc0[jt][n];
      float f[4];
      #pragma unroll
      for (int q = 0; q < 4; ++q) {
        const int j = j0 + q;
        f[q] = (j > gk0) ? a[q] : ((j == gk0) ? 0.5f * a[q] : 0.f);
      }
      u32x2 pk; pk[0] = cvt2(f[0], f[1]); pk[1] = cvt2(f[2], f[3]);
      *(u32x2*)(H + swzL(n * 16 + lr, j0)) = pk;
      a = acc1[jt][n];
      #pragma unroll
      for (int q = 0; q < 4; ++q) {
        const int j = j0 + q;
        f[q] = (j > gk1) ? a[q] : ((j == gk1) ? 0.5f * a[q] : 0.f);
      }
      pk[0] = cvt2(f[0], f[1]); pk[1] = cvt2(f[2], f[3]);
      *(u32x2*)(H + swzL(64 + n * 16 + lr, j0)) = pk;
    }
  }
  __syncthreads();   // barrier 5: phi panels ready

  // ---- Phase D: out = -LR @ phi
  #pragma unroll
  for (int m = 0; m < 4; ++m)
    #pragma unroll
    for (int n = 0; n < 4; ++n) { acc0[m][n] = (f32x4)0.f; acc1[m][n] = (f32x4)0.f; }
  phase_v8(LRb, H, acc0, acc1, w, lr, lq);

  #pragma unroll
  for (int m = 0; m < 4; ++m) {
    const int i0 = w * 64 + m * 16 + lq * 4;
    #pragma unroll
    for (int n = 0; n < 4; ++n) {
      const int col = c0 + n * 16 + lr;
      f32x4 a = acc0[m][n];
      #pragma unroll
      for (int q = 0; q < 4; ++q)
        Ob[(size_t)(i0 + q) * NV + col] = -a[q];
      a = acc1[m][n];
      #pragma unroll
      for (int q = 0; q < 4; ++q)
        Ob[(size_t)(i0 + q) * NV + col + 64] = -a[q];
    }
  }
}

// ---------------------------------------------------------------------------
// LT-only fast path (R2 form) for 64MB <= ws < 192MB
// ---------------------------------------------------------------------------
__global__ __launch_bounds__(1024, 1)
void fused_cholTE_fast(const float* __restrict__ covTE,
                       const float* __restrict__ chol,
                       const unsigned short* __restrict__ LT,
                       float* __restrict__ out) {
  __shared__ __align__(16) char lds[131072];
  char* sB0 = lds;
  char* sB1 = lds + 65536;

  const int tid  = threadIdx.x;
  const int w    = tid >> 6;
  const int lane = tid & 63;
  const int lr   = lane & 15;
  const int lq   = lane >> 4;

  const int bid = blockIdx.x;
  const int xcd = bid & 7;
  const int s   = bid >> 3;
  const int b   = xcd * 16 + (s >> 3);
  const int c0  = (s & 7) * NC;

  const float*          Cb  = covTE + (size_t)b * NV * NV;
  const float*          Lb  = chol  + (size_t)b * NV * NV;
  const unsigned short* LTb = LT    + (size_t)b * NV * NV;
  float*                Ob  = out   + (size_t)b * NV * NV;

  #pragma unroll
  for (int cc = 0; cc < 4; ++cc) {
    const int c = cc * 16 + w;
    const unsigned short* src = LTb + (size_t)(c0 + c) * NV + ((lane ^ (c & 7)) * 8);
    gload_lds16(src, sB0 + c * 1024);
  }
  __syncthreads();

  f32x4 acc[2][4];
  #pragma unroll
  for (int m = 0; m < 2; ++m)
    #pragma unroll
    for (int n = 0; n < 4; ++n) acc[m][n] = (f32x4)0.f;

  for (int kb = 0; kb < 16; ++kb) {
    const int kbase = kb * 32 + lq * 8;
    bf8 bfr[4];
    #pragma unroll
    for (int n = 0; n < 4; ++n)
      bfr[n] = *(const bf8*)(sB0 + swzL(n * 16 + lr, kbase));
    #pragma unroll
    for (int m = 0; m < 2; ++m) {
      const float* p = Cb + (size_t)(w * 32 + m * 16 + lr) * NV + kbase;
      fv4 a0 = *(const fv4*)p;
      fv4 a1 = *(const fv4*)(p + 4);
      bf8 af = pack8(a0, a1);
      #pragma unroll
      for (int n = 0; n < 4; ++n)
        acc[m][n] = __builtin_amdgcn_mfma_f32_16x16x32_bf16(af, bfr[n], acc[m][n], 0, 0, 0);
    }
  }
  #pragma unroll
  for (int m = 0; m < 2; ++m) {
    #pragma unroll
    for (int n = 0; n < 4; ++n) {
      f32x4 a = acc[m][n];
      u32x2 pk; pk[0] = cvt2(a[0], a[1]); pk[1] = cvt2(a[2], a[3]);
      *(u32x2*)(sB1 + swzL(n * 16 + lr, w * 32 + m * 16 + lq * 4)) = pk;
    }
  }
  __syncthreads();

  #pragma unroll
  for (int m = 0; m < 2; ++m)
    #pragma unroll
    for (int n = 0; n < 4; ++n) acc[m][n] = (f32x4)0.f;

  for (int ib = 0; ib < 16; ++ib) {
    const int kbase = ib * 32 + lq * 8;
    bf8 bt[4];
    #pragma unroll
    for (int n = 0; n < 4; ++n)
      bt[n] = *(const bf8*)(sB1 + swzL(n * 16 + lr, kbase));
    #pragma unroll
    for (int jt = 0; jt < 2; ++jt) {
      bf8 af = *(const bf8*)(LTb + (size_t)(w * 32 + jt * 16 + lr) * NV + kbase);
      #pragma unroll
      for (int n = 0; n < 4; ++n)
        acc[jt][n] = __builtin_amdgcn_mfma_f32_16x16x32_bf16(af, bt[n], acc[jt][n], 0, 0, 0);
    }
  }
  #pragma unroll
  for (int jt = 0; jt < 2; ++jt) {
    #pragma unroll
    for (int n = 0; n < 4; ++n) {
      f32x4 a = acc[jt][n];
      const int gk = c0 + n * 16 + lr;
      const int j0 = w * 32 + jt * 16 + lq * 4;
      float f[4];
      #pragma unroll
      for (int q = 0; q < 4; ++q) {
        const int j = j0 + q;
        f[q] = (j > gk) ? a[q] : ((j == gk) ? 0.5f * a[q] : 0.f);
      }
      u32x2 pk; pk[0] = cvt2(f[0], f[1]); pk[1] = cvt2(f[2], f[3]);
      *(u32x2*)(sB0 + swzL(n * 16 + lr, j0)) = pk;
    }
  }
  __syncthreads();

  #pragma unroll
  for (int m = 0; m < 2; ++m)
    #pragma unroll
    for (int n = 0; n < 4; ++n) acc[m][n] = (f32x4)0.f;

  for (int kb = 0; kb < 16; ++kb) {
    const int kbase = kb * 32 + lq * 8;
    bf8 bp[4];
    #pragma unroll
    for (int n = 0; n < 4; ++n)
      bp[n] = *(const bf8*)(sB0 + swzL(n * 16 + lr, kbase));
    #pragma unroll
    for (int m = 0; m < 2; ++m) {
      const float* p = Lb + (size_t)(w * 32 + m * 16 + lr) * NV + kbase;
      fv4 a0 = *(const fv4*)p;
      fv4 a1 = *(const fv4*)(p + 4);
      bf8 af = pack8(a0, a1);
      #pragma unroll
      for (int n = 0; n < 4; ++n)
        acc[m][n] = __builtin_amdgcn_mfma_f32_16x16x32_bf16(af, bp[n], acc[m][n], 0, 0, 0);
    }
  }
  #pragma unroll
  for (int m = 0; m < 2; ++m) {
    const int i0 = w * 32 + m * 16 + lq * 4;
    #pragma unroll
    for (int n = 0; n < 4; ++n) {
      f32x4 a = acc[m][n];
      const int col = c0 + n * 16 + lr;
      #pragma unroll
      for (int q = 0; q < 4; ++q)
        Ob[(size_t)(i0 + q) * NV + col] = -a[q];
    }
  }
}

// ---------------------------------------------------------------------------
// No-workspace fallback (R1 form)
// ---------------------------------------------------------------------------
__global__ __launch_bounds__(1024, 1)
void fused_cholTE_fallback(const float* __restrict__ covTE,
                           const float* __restrict__ chol,
                           float* __restrict__ out) {
  __shared__ __align__(16) char lds[131072];
  char* sB0 = lds;
  char* sB1 = lds + 65536;
  char* sCh = lds;

  const int tid  = threadIdx.x;
  const int w    = tid >> 6;
  const int lane = tid & 63;
  const int lr   = lane & 15;
  const int lq   = lane >> 4;

  const int bid = blockIdx.x;
  const int xcd = bid & 7;
  const int s   = bid >> 3;
  const int b   = xcd * 16 + (s >> 3);
  const int c0  = (s & 7) * NC;

  const float* Cb = covTE + (size_t)b * NV * NV;
  const float* Lb = chol  + (size_t)b * NV * NV;
  float*       Ob = out   + (size_t)b * NV * NV;

  {
    const int rr = tid >> 4;
    const int cc = (tid & 15) * 4;
    #pragma unroll
    for (int p = 0; p < 8; ++p) {
      const int r = p * 64 + rr;
      fv4 v = *(const fv4*)(Lb + (size_t)r * NV + c0 + cc);
      *(unsigned short*)(sB0 + swzL(cc + 0, r)) = f2bf(v[0]);
      *(unsigned short*)(sB0 + swzL(cc + 1, r)) = f2bf(v[1]);
      *(unsigned short*)(sB0 + swzL(cc + 2, r)) = f2bf(v[2]);
      *(unsigned short*)(sB0 + swzL(cc + 3, r)) = f2bf(v[3]);
    }
  }
  __syncthreads();

  f32x4 acc[2][4];
  #pragma unroll
  for (int m = 0; m < 2; ++m)
    #pragma unroll
    for (int n = 0; n < 4; ++n) acc[m][n] = (f32x4)0.f;

  for (int kb = 0; kb < 16; ++kb) {
    const int kbase = kb * 32 + lq * 8;
    bf8 bfr[4];
    #pragma unroll
    for (int n = 0; n < 4; ++n)
      bfr[n] = *(const bf8*)(sB0 + swzL(n * 16 + lr, kbase));
    #pragma unroll
    for (int m = 0; m < 2; ++m) {
      const float* p = Cb + (size_t)(w * 32 + m * 16 + lr) * NV + kbase;
      fv4 a0 = *(const fv4*)p;
      fv4 a1 = *(const fv4*)(p + 4);
      bf8 af = pack8(a0, a1);
      #pragma unroll
      for (int n = 0; n < 4; ++n)
        acc[m][n] = __builtin_amdgcn_mfma_f32_16x16x32_bf16(af, bfr[n], acc[m][n], 0, 0, 0);
    }
  }
  #pragma unroll
  for (int m = 0; m < 2; ++m) {
    #pragma unroll
    for (int n = 0; n < 4; ++n) {
      f32x4 a = acc[m][n];
      u32x2 pk; pk[0] = cvt2(a[0], a[1]); pk[1] = cvt2(a[2], a[3]);
      *(u32x2*)(sB1 + swzL(n * 16 + lr, w * 32 + m * 16 + lq * 4)) = pk;
    }
  }
  __syncthreads();

  #pragma unroll
  for (int m = 0; m < 2; ++m)
    #pragma unroll
    for (int n = 0; n < 4; ++n) acc[m][n] = (f32x4)0.f;

  const int sj = (tid & 255) * 2;
  const int so = tid >> 8;

  fv2 raw[8];
  {
    const float* src = Lb + (size_t)(so * 8) * NV + sj;
    #pragma unroll
    for (int r = 0; r < 8; ++r) raw[r] = *(const fv2*)(src + (size_t)r * NV);
    u16x8 p0, p1;
    #pragma unroll
    for (int r = 0; r < 8; ++r) { p0[r] = f2bf(raw[r][0]); p1[r] = f2bf(raw[r][1]); }
    *(u16x8*)(sCh + swzC(sj + 0, so * 8)) = p0;
    *(u16x8*)(sCh + swzC(sj + 1, so * 8)) = p1;
  }
  __syncthreads();

  for (int ib = 0; ib < 16; ++ib) {
    if (ib + 1 < 16) {
      const float* src = Lb + (size_t)((ib + 1) * 32 + so * 8) * NV + sj;
      #pragma unroll
      for (int r = 0; r < 8; ++r) raw[r] = *(const fv2*)(src + (size_t)r * NV);
    }
    bf8 bt[4];
    #pragma unroll
    for (int n = 0; n < 4; ++n)
      bt[n] = *(const bf8*)(sB1 + swzL(n * 16 + lr, ib * 32 + lq * 8));
    #pragma unroll
    for (int jt = 0; jt < 2; ++jt) {
      bf8 af = *(const bf8*)(sCh + swzC(w * 32 + jt * 16 + lr, lq * 8));
      #pragma unroll
      for (int n = 0; n < 4; ++n)
        acc[jt][n] = __builtin_amdgcn_mfma_f32_16x16x32_bf16(af, bt[n], acc[jt][n], 0, 0, 0);
    }
    __syncthreads();
    if (ib + 1 < 16) {
      u16x8 p0, p1;
      #pragma unroll
      for (int r = 0; r < 8; ++r) { p0[r] = f2bf(raw[r][0]); p1[r] = f2bf(raw[r][1]); }
      *(u16x8*)(sCh + swzC(sj + 0, so * 8)) = p0;
      *(u16x8*)(sCh + swzC(sj + 1, so * 8)) = p1;
    }
    __syncthreads();
  }

  #pragma unroll
  for (int jt = 0; jt < 2; ++jt) {
    #pragma unroll
    for (int n = 0; n < 4; ++n) {
      f32x4 a = acc[jt][n];
      const int gk = c0 + n * 16 + lr;
      const int j0 = w * 32 + jt * 16 + lq * 4;
      float f[4];
      #pragma unroll
      for (int q = 0; q < 4; ++q) {
        const int j = j0 + q;
        f[q] = (j > gk) ? a[q] : ((j == gk) ? 0.5f * a[q] : 0.f);
      }
      u32x2 pk; pk[0] = cvt2(f[0], f[1]); pk[1] = cvt2(f[2], f[3]);
      *(u32x2*)(sB0 + swzL(n * 16 + lr, j0)) = pk;
    }
  }
  __syncthreads();

  #pragma unroll
  for (int m = 0; m < 2; ++m)
    #pragma unroll
    for (int n = 0; n < 4; ++n) acc[m][n] = (f32x4)0.f;

  for (int kb = 0; kb < 16; ++kb) {
    const int kbase = kb * 32 + lq * 8;
    bf8 bp[4];
    #pragma unroll
    for (int n = 0; n < 4; ++n)
      bp[n] = *(const bf8*)(sB0 + swzL(n * 16 + lr, kbase));
    #pragma unroll
    for (int m = 0; m < 2; ++m) {
      const float* p = Lb + (size_t)(w * 32 + m * 16 + lr) * NV + kbase;
      fv4 a0 = *(const fv4*)p;
      fv4 a1 = *(const fv4*)(p + 4);
      bf8 af = pack8(a0, a1);
      #pragma unroll
      for (int n = 0; n < 4; ++n)
        acc[m][n] = __builtin_amdgcn_mfma_f32_16x16x32_bf16(af, bp[n], acc[m][n], 0, 0, 0);
    }
  }
  #pragma unroll
  for (int m = 0; m < 2; ++m) {
    const int i0 = w * 32 + m * 16 + lq * 4;
    #pragma unroll
    for (int n = 0; n < 4; ++n) {
      f32x4 a = acc[m][n];
      const int col = c0 + n * 16 + lr;
      #pragma unroll
      for (int q = 0; q < 4; ++q)
        Ob[(size_t)(i0 + q) * NV + col] = -a[q];
    }
  }
}

extern "C" void kernel_launch(void* const* d_in, const int* in_sizes, int n_in,
                              void* d_out, int out_size, void* d_ws, size_t ws_size,
                              hipStream_t stream) {
  const float* muTE  = (const float*)d_in[0];
  const float* covTE = (const float*)d_in[1];
  const float* chol  = (const float*)d_in[2];
  float* out = (float*)d_out;

  (void)hipMemcpyAsync(out, muTE, (size_t)NB * NV * sizeof(float),
                       hipMemcpyDeviceToDevice, stream);

  float* cholTE = out + (size_t)NB * NV;
  const size_t nmat     = (size_t)NB * NV * NV;          // 33,554,432 elems
  const size_t lt_bytes = nmat * sizeof(unsigned short); // 64 MiB

  if (ws_size >= 3 * lt_bytes) {
    unsigned short* CV = (unsigned short*)d_ws;
    unsigned short* LR = CV + nmat;
    unsigned short* LT = LR + nmat;
    conv_f32_bf16_kernel<<<dim3(nmat / (256 * 8)), dim3(256), 0, stream>>>(covTE, CV);
    convert_LT_kernel<<<dim3(NB * 64), dim3(256), 0, stream>>>(chol, LT, LR);
    fused_cholTE_v8<<<dim3(NB * 4), dim3(512), 0, stream>>>(CV, LR, LT, cholTE);
  } else if (ws_size >= lt_bytes) {
    unsigned short* LT = (unsigned short*)d_ws;
    convert_LT_kernel<<<dim3(NB * 64), dim3(256), 0, stream>>>(chol, LT, nullptr);
    fused_cholTE_fast<<<dim3(NB * (NV / NC)), dim3(1024), 0, stream>>>(
        covTE, chol, LT, cholTE);
  } else {
    fused_cholTE_fallback<<<dim3(NB * (NV / NC)), dim3(1024), 0, stream>>>(
        covTE, chol, cholTE);
  }
}

// Round 14
// 239.111 us; speedup vs baseline: 1.9953x; 1.0058x over previous
//
#include <hip/hip_runtime.h>
#include <hip/hip_bf16.h>

#define NV 512
#define NB 128
#define NC 64

typedef float fv4 __attribute__((ext_vector_type(4)));
typedef float fv2 __attribute__((ext_vector_type(2)));
typedef float f32x4 __attribute__((ext_vector_type(4)));
typedef short bf8 __attribute__((ext_vector_type(8)));            // 8 bf16 (MFMA A/B frag)
typedef unsigned short u16x4 __attribute__((ext_vector_type(4)));
typedef unsigned short u16x8 __attribute__((ext_vector_type(8)));
typedef unsigned u32x2 __attribute__((ext_vector_type(2)));
typedef unsigned u32x4 __attribute__((ext_vector_type(4)));

// f32 -> bf16 RNE, scalar
__device__ __forceinline__ unsigned short f2bf(float f) {
  unsigned u = __builtin_bit_cast(unsigned, f);
  u += 0x7fffu + ((u >> 16) & 1u);
  return (unsigned short)(u >> 16);
}

// packed f32x2 -> bf16x2 (v_cvt_pk_bf16_f32)
__device__ __forceinline__ unsigned cvt2(float lo, float hi) {
  __hip_bfloat162 h = __float22bfloat162_rn(make_float2(lo, hi));
  unsigned r;
  __builtin_memcpy(&r, &h, sizeof(r));
  return r;
}

__device__ __forceinline__ bf8 pack8(fv4 a0, fv4 a1) {
  u32x4 r;
  r[0] = cvt2(a0[0], a0[1]);
  r[1] = cvt2(a0[2], a0[3]);
  r[2] = cvt2(a1[0], a1[1]);
  r[3] = cvt2(a1[2], a1[3]);
  return __builtin_bit_cast(bf8, r);
}

// panel: [cols][512 rows] bf16, 1KB per col; XOR swizzle on 16B granules
__device__ __forceinline__ int swzL(int c, int r) {
  return ((c << 10) + (r << 1)) ^ ((c & 7) << 4);
}
// fallback staging layout
__device__ __forceinline__ int swzC(int j, int ii) {
  return ((j << 6) + (ii << 1)) ^ ((j & 3) << 4);
}

__device__ __forceinline__ void gload_lds16(const void* g, void* l) {
  __builtin_amdgcn_global_load_lds(
      (const __attribute__((address_space(1))) unsigned int*)g,
      (__attribute__((address_space(3))) unsigned int*)l, 16, 0, 0);
}

// ---------------------------------------------------------------------------
// Convert kernel: LT[b][j][i] = bf16(chol[b][i][j])   (64 MiB workspace)
// ---------------------------------------------------------------------------
__global__ __launch_bounds__(256, 4)
void convert_LT_kernel(const float* __restrict__ chol,
                       unsigned short* __restrict__ LT) {
  __shared__ unsigned short T[64][72];
  const int bid = blockIdx.x;
  const int b  = bid >> 6;
  const int t  = bid & 63;
  const int ti = t >> 3, tj = t & 7;

  const float* src = chol + ((size_t)b * NV + ti * 64) * NV + tj * 64;
  {
    const int r0 = threadIdx.x >> 4;
    const int c4 = (threadIdx.x & 15) * 4;
    #pragma unroll
    for (int p = 0; p < 4; ++p) {
      const int r = p * 16 + r0;
      fv4 v = *(const fv4*)(src + (size_t)r * NV + c4);
      T[c4 + 0][r] = f2bf(v[0]);
      T[c4 + 1][r] = f2bf(v[1]);
      T[c4 + 2][r] = f2bf(v[2]);
      T[c4 + 3][r] = f2bf(v[3]);
    }
  }
  __syncthreads();
  unsigned short* dst = LT + ((size_t)b * NV + tj * 64) * NV + ti * 64;
  const int c  = threadIdx.x >> 2;
  const int k8 = (threadIdx.x & 3) * 16;
  u16x8 o0, o1;
  #pragma unroll
  for (int q = 0; q < 8; ++q) { o0[q] = T[c][k8 + q]; o1[q] = T[c][k8 + 8 + q]; }
  *(u16x8*)(dst + (size_t)c * NV + k8)     = o0;
  *(u16x8*)(dst + (size_t)c * NV + k8 + 8) = o1;
}

// ---------------------------------------------------------------------------
// v9 main kernel: v8 geometry (512 thr, 2 waves/SIMD, 2x64-col panels,
// 128KB LDS, 5 barriers, acc0+acc1 = 128 AGPR). Phases B and D read their
// A-operand DIRECTLY from f32 global with in-loop cvt_pk pack — the 32-MFMA
// blocks per iter hide the VALU. Only LT (transposed chol bf16) is needed.
// ---------------------------------------------------------------------------

// A from f32 global (in-loop pack), B from two LDS panels
__device__ __forceinline__ void phase_v9_f32(const float* Abase,
                                             const char* H,
                                             f32x4 (&acc0)[4][4], f32x4 (&acc1)[4][4],
                                             int w, int lr, int lq) {
  const float* rA = Abase + (size_t)(w * 64 + lr) * NV + lq * 8;
  #pragma unroll 2
  for (int t = 0; t < 16; ++t) {
    const int kbase = t * 32 + lq * 8;
    bf8 a[4];
    #pragma unroll
    for (int m = 0; m < 4; ++m) {
      fv4 f0 = *(const fv4*)(rA + (size_t)(m * 16) * NV + t * 32);
      fv4 f1 = *(const fv4*)(rA + (size_t)(m * 16) * NV + t * 32 + 4);
      a[m] = pack8(f0, f1);
    }
    bf8 b0[4];
    #pragma unroll
    for (int n = 0; n < 4; ++n)
      b0[n] = *(const bf8*)(H + swzL(n * 16 + lr, kbase));
    #pragma unroll
    for (int m = 0; m < 4; ++m)
      #pragma unroll
      for (int n = 0; n < 4; ++n)
        acc0[m][n] = __builtin_amdgcn_mfma_f32_16x16x32_bf16(a[m], b0[n], acc0[m][n], 0, 0, 0);
    bf8 b1[4];
    #pragma unroll
    for (int n = 0; n < 4; ++n)
      b1[n] = *(const bf8*)(H + swzL(64 + n * 16 + lr, kbase));
    #pragma unroll
    for (int m = 0; m < 4; ++m)
      #pragma unroll
      for (int n = 0; n < 4; ++n)
        acc1[m][n] = __builtin_amdgcn_mfma_f32_16x16x32_bf16(a[m], b1[n], acc1[m][n], 0, 0, 0);
  }
}

// A from bf16 global (LT), B from two LDS panels  (phase C)
__device__ __forceinline__ void phase_v9_bf16(const unsigned short* Abase,
                                              const char* H,
                                              f32x4 (&acc0)[4][4], f32x4 (&acc1)[4][4],
                                              int w, int lr, int lq) {
  const unsigned short* rA = Abase + (size_t)(w * 64 + lr) * NV + lq * 8;
  #pragma unroll 2
  for (int t = 0; t < 16; ++t) {
    const int kbase = t * 32 + lq * 8;
    bf8 a[4];
    #pragma unroll
    for (int m = 0; m < 4; ++m)
      a[m] = *(const bf8*)(rA + (size_t)(m * 16) * NV + t * 32);
    bf8 b0[4];
    #pragma unroll
    for (int n = 0; n < 4; ++n)
      b0[n] = *(const bf8*)(H + swzL(n * 16 + lr, kbase));
    #pragma unroll
    for (int m = 0; m < 4; ++m)
      #pragma unroll
      for (int n = 0; n < 4; ++n)
        acc0[m][n] = __builtin_amdgcn_mfma_f32_16x16x32_bf16(a[m], b0[n], acc0[m][n], 0, 0, 0);
    bf8 b1[4];
    #pragma unroll
    for (int n = 0; n < 4; ++n)
      b1[n] = *(const bf8*)(H + swzL(64 + n * 16 + lr, kbase));
    #pragma unroll
    for (int m = 0; m < 4; ++m)
      #pragma unroll
      for (int n = 0; n < 4; ++n)
        acc1[m][n] = __builtin_amdgcn_mfma_f32_16x16x32_bf16(a[m], b1[n], acc1[m][n], 0, 0, 0);
  }
}

__global__ __launch_bounds__(512, 2)
void fused_cholTE_v9(const float* __restrict__ covTE,
                     const float* __restrict__ chol,
                     const unsigned short* __restrict__ LT,
                     float* __restrict__ out) {
  __shared__ __align__(16) char H[131072];   // 128 cols x 1KB: cholC -> T1 -> phi

  const int tid  = threadIdx.x;
  const int w    = tid >> 6;     // wave 0..7
  const int lane = tid & 63;
  const int lr   = lane & 15;
  const int lq   = lane >> 4;

  // 512 WGs: xcd = bid%8; per XCD 16 batches x 4 col-pairs, batch-major
  const int bid = blockIdx.x;
  const int xcd = bid & 7;
  const int s   = bid >> 3;            // 0..63
  const int b   = xcd * 16 + (s >> 2); // batch
  const int c0  = (s & 3) * 128;       // column pair base (two 64-col panels)

  const float*          Cb  = covTE + (size_t)b * NV * NV;
  const float*          Lb  = chol  + (size_t)b * NV * NV;
  const unsigned short* LTb = LT    + (size_t)b * NV * NV;
  float*                Ob  = out   + (size_t)b * NV * NV;

  f32x4 acc0[4][4], acc1[4][4];

  // ---- stage both cholC panels: LT rows c0..c0+127 -> H (source-swizzled)
  #pragma unroll
  for (int cc = 0; cc < 16; ++cc) {
    const int c = cc * 8 + w;
    const unsigned short* src = LTb + (size_t)(c0 + c) * NV + ((lane ^ (c & 7)) * 8);
    gload_lds16(src, H + c * 1024);
  }
  asm volatile("s_waitcnt vmcnt(0)" ::: "memory");
  __syncthreads();   // barrier 1: cholC panels ready

  // ---- Phase B: T1 = covTE(f32) @ cholC
  #pragma unroll
  for (int m = 0; m < 4; ++m)
    #pragma unroll
    for (int n = 0; n < 4; ++n) { acc0[m][n] = (f32x4)0.f; acc1[m][n] = (f32x4)0.f; }
  phase_v9_f32(Cb, H, acc0, acc1, w, lr, lq);
  __syncthreads();   // barrier 2: done reading cholC

  // T1 -> H (overwrite)
  #pragma unroll
  for (int m = 0; m < 4; ++m) {
    #pragma unroll
    for (int n = 0; n < 4; ++n) {
      const int rrow = w * 64 + m * 16 + lq * 4;
      f32x4 a = acc0[m][n];
      u32x2 pk; pk[0] = cvt2(a[0], a[1]); pk[1] = cvt2(a[2], a[3]);
      *(u32x2*)(H + swzL(n * 16 + lr, rrow)) = pk;
      a = acc1[m][n];
      pk[0] = cvt2(a[0], a[1]); pk[1] = cvt2(a[2], a[3]);
      *(u32x2*)(H + swzL(64 + n * 16 + lr, rrow)) = pk;
    }
  }
  __syncthreads();   // barrier 3: T1 panels ready

  // ---- Phase C: phi = LT-rows(bf16) @ T1 (masked)
  #pragma unroll
  for (int m = 0; m < 4; ++m)
    #pragma unroll
    for (int n = 0; n < 4; ++n) { acc0[m][n] = (f32x4)0.f; acc1[m][n] = (f32x4)0.f; }
  phase_v9_bf16(LTb, H, acc0, acc1, w, lr, lq);
  __syncthreads();   // barrier 4: done reading T1

  // mask (strict lower=1, diag=0.5, upper=0); phi -> H (overwrite)
  #pragma unroll
  for (int jt = 0; jt < 4; ++jt) {
    #pragma unroll
    for (int n = 0; n < 4; ++n) {
      const int j0 = w * 64 + jt * 16 + lq * 4;
      const int gk0 = c0 + n * 16 + lr;
      const int gk1 = gk0 + 64;
      f32x4 a = acc0[jt][n];
      float f[4];
      #pragma unroll
      for (int q = 0; q < 4; ++q) {
        const int j = j0 + q;
        f[q] = (j > gk0) ? a[q] : ((j == gk0) ? 0.5f * a[q] : 0.f);
      }
      u32x2 pk; pk[0] = cvt2(f[0], f[1]); pk[1] = cvt2(f[2], f[3]);
      *(u32x2*)(H + swzL(n * 16 + lr, j0)) = pk;
      a = acc1[jt][n];
      #pragma unroll
      for (int q = 0; q < 4; ++q) {
        const int j = j0 + q;
        f[q] = (j > gk1) ? a[q] : ((j == gk1) ? 0.5f * a[q] : 0.f);
      }
      pk[0] = cvt2(f[0], f[1]); pk[1] = cvt2(f[2], f[3]);
      *(u32x2*)(H + swzL(64 + n * 16 + lr, j0)) = pk;
    }
  }
  __syncthreads();   // barrier 5: phi panels ready

  // ---- Phase D: out = -chol(f32) @ phi
  #pragma unroll
  for (int m = 0; m < 4; ++m)
    #pragma unroll
    for (int n = 0; n < 4; ++n) { acc0[m][n] = (f32x4)0.f; acc1[m][n] = (f32x4)0.f; }
  phase_v9_f32(Lb, H, acc0, acc1, w, lr, lq);

  #pragma unroll
  for (int m = 0; m < 4; ++m) {
    const int i0 = w * 64 + m * 16 + lq * 4;
    #pragma unroll
    for (int n = 0; n < 4; ++n) {
      const int col = c0 + n * 16 + lr;
      f32x4 a = acc0[m][n];
      #pragma unroll
      for (int q = 0; q < 4; ++q)
        Ob[(size_t)(i0 + q) * NV + col] = -a[q];
      a = acc1[m][n];
      #pragma unroll
      for (int q = 0; q < 4; ++q)
        Ob[(size_t)(i0 + q) * NV + col + 64] = -a[q];
    }
  }
}

// ---------------------------------------------------------------------------
// No-workspace fallback (R1 form)
// ---------------------------------------------------------------------------
__global__ __launch_bounds__(1024, 1)
void fused_cholTE_fallback(const float* __restrict__ covTE,
                           const float* __restrict__ chol,
                           float* __restrict__ out) {
  __shared__ __align__(16) char lds[131072];
  char* sB0 = lds;
  char* sB1 = lds + 65536;
  char* sCh = lds;

  const int tid  = threadIdx.x;
  const int w    = tid >> 6;
  const int lane = tid & 63;
  const int lr   = lane & 15;
  const int lq   = lane >> 4;

  const int bid = blockIdx.x;
  const int xcd = bid & 7;
  const int s   = bid >> 3;
  const int b   = xcd * 16 + (s >> 3);
  const int c0  = (s & 7) * NC;

  const float* Cb = covTE + (size_t)b * NV * NV;
  const float* Lb = chol  + (size_t)b * NV * NV;
  float*       Ob = out   + (size_t)b * NV * NV;

  {
    const int rr = tid >> 4;
    const int cc = (tid & 15) * 4;
    #pragma unroll
    for (int p = 0; p < 8; ++p) {
      const int r = p * 64 + rr;
      fv4 v = *(const fv4*)(Lb + (size_t)r * NV + c0 + cc);
      *(unsigned short*)(sB0 + swzL(cc + 0, r)) = f2bf(v[0]);
      *(unsigned short*)(sB0 + swzL(cc + 1, r)) = f2bf(v[1]);
      *(unsigned short*)(sB0 + swzL(cc + 2, r)) = f2bf(v[2]);
      *(unsigned short*)(sB0 + swzL(cc + 3, r)) = f2bf(v[3]);
    }
  }
  __syncthreads();

  f32x4 acc[2][4];
  #pragma unroll
  for (int m = 0; m < 2; ++m)
    #pragma unroll
    for (int n = 0; n < 4; ++n) acc[m][n] = (f32x4)0.f;

  for (int kb = 0; kb < 16; ++kb) {
    const int kbase = kb * 32 + lq * 8;
    bf8 bfr[4];
    #pragma unroll
    for (int n = 0; n < 4; ++n)
      bfr[n] = *(const bf8*)(sB0 + swzL(n * 16 + lr, kbase));
    #pragma unroll
    for (int m = 0; m < 2; ++m) {
      const float* p = Cb + (size_t)(w * 32 + m * 16 + lr) * NV + kbase;
      fv4 a0 = *(const fv4*)p;
      fv4 a1 = *(const fv4*)(p + 4);
      bf8 af = pack8(a0, a1);
      #pragma unroll
      for (int n = 0; n < 4; ++n)
        acc[m][n] = __builtin_amdgcn_mfma_f32_16x16x32_bf16(af, bfr[n], acc[m][n], 0, 0, 0);
    }
  }
  #pragma unroll
  for (int m = 0; m < 2; ++m) {
    #pragma unroll
    for (int n = 0; n < 4; ++n) {
      f32x4 a = acc[m][n];
      u32x2 pk; pk[0] = cvt2(a[0], a[1]); pk[1] = cvt2(a[2], a[3]);
      *(u32x2*)(sB1 + swzL(n * 16 + lr, w * 32 + m * 16 + lq * 4)) = pk;
    }
  }
  __syncthreads();

  #pragma unroll
  for (int m = 0; m < 2; ++m)
    #pragma unroll
    for (int n = 0; n < 4; ++n) acc[m][n] = (f32x4)0.f;

  const int sj = (tid & 255) * 2;
  const int so = tid >> 8;

  fv2 raw[8];
  {
    const float* src = Lb + (size_t)(so * 8) * NV + sj;
    #pragma unroll
    for (int r = 0; r < 8; ++r) raw[r] = *(const fv2*)(src + (size_t)r * NV);
    u16x8 p0, p1;
    #pragma unroll
    for (int r = 0; r < 8; ++r) { p0[r] = f2bf(raw[r][0]); p1[r] = f2bf(raw[r][1]); }
    *(u16x8*)(sCh + swzC(sj + 0, so * 8)) = p0;
    *(u16x8*)(sCh + swzC(sj + 1, so * 8)) = p1;
  }
  __syncthreads();

  for (int ib = 0; ib < 16; ++ib) {
    if (ib + 1 < 16) {
      const float* src = Lb + (size_t)((ib + 1) * 32 + so * 8) * NV + sj;
      #pragma unroll
      for (int r = 0; r < 8; ++r) raw[r] = *(const fv2*)(src + (size_t)r * NV);
    }
    bf8 bt[4];
    #pragma unroll
    for (int n = 0; n < 4; ++n)
      bt[n] = *(const bf8*)(sB1 + swzL(n * 16 + lr, ib * 32 + lq * 8));
    #pragma unroll
    for (int jt = 0; jt < 2; ++jt) {
      bf8 af = *(const bf8*)(sCh + swzC(w * 32 + jt * 16 + lr, lq * 8));
      #pragma unroll
      for (int n = 0; n < 4; ++n)
        acc[jt][n] = __builtin_amdgcn_mfma_f32_16x16x32_bf16(af, bt[n], acc[jt][n], 0, 0, 0);
    }
    __syncthreads();
    if (ib + 1 < 16) {
      u16x8 p0, p1;
      #pragma unroll
      for (int r = 0; r < 8; ++r) { p0[r] = f2bf(raw[r][0]); p1[r] = f2bf(raw[r][1]); }
      *(u16x8*)(sCh + swzC(sj + 0, so * 8)) = p0;
      *(u16x8*)(sCh + swzC(sj + 1, so * 8)) = p1;
    }
    __syncthreads();
  }

  #pragma unroll
  for (int jt = 0; jt < 2; ++jt) {
    #pragma unroll
    for (int n = 0; n < 4; ++n) {
      f32x4 a = acc[jt][n];
      const int gk = c0 + n * 16 + lr;
      const int j0 = w * 32 + jt * 16 + lq * 4;
      float f[4];
      #pragma unroll
      for (int q = 0; q < 4; ++q) {
        const int j = j0 + q;
        f[q] = (j > gk) ? a[q] : ((j == gk) ? 0.5f * a[q] : 0.f);
      }
      u32x2 pk; pk[0] = cvt2(f[0], f[1]); pk[1] = cvt2(f[2], f[3]);
      *(u32x2*)(sB0 + swzL(n * 16 + lr, j0)) = pk;
    }
  }
  __syncthreads();

  #pragma unroll
  for (int m = 0; m < 2; ++m)
    #pragma unroll
    for (int n = 0; n < 4; ++n) acc[m][n] = (f32x4)0.f;

  for (int kb = 0; kb < 16; ++kb) {
    const int kbase = kb * 32 + lq * 8;
    bf8 bp[4];
    #pragma unroll
    for (int n = 0; n < 4; ++n)
      bp[n] = *(const bf8*)(sB0 + swzL(n * 16 + lr, kbase));
    #pragma unroll
    for (int m = 0; m < 2; ++m) {
      const float* p = Lb + (size_t)(w * 32 + m * 16 + lr) * NV + kbase;
      fv4 a0 = *(const fv4*)p;
      fv4 a1 = *(const fv4*)(p + 4);
      bf8 af = pack8(a0, a1);
      #pragma unroll
      for (int n = 0; n < 4; ++n)
        acc[m][n] = __builtin_amdgcn_mfma_f32_16x16x32_bf16(af, bp[n], acc[m][n], 0, 0, 0);
    }
  }
  #pragma unroll
  for (int m = 0; m < 2; ++m) {
    const int i0 = w * 32 + m * 16 + lq * 4;
    #pragma unroll
    for (int n = 0; n < 4; ++n) {
      f32x4 a = acc[m][n];
      const int col = c0 + n * 16 + lr;
      #pragma unroll
      for (int q = 0; q < 4; ++q)
        Ob[(size_t)(i0 + q) * NV + col] = -a[q];
    }
  }
}

extern "C" void kernel_launch(void* const* d_in, const int* in_sizes, int n_in,
                              void* d_out, int out_size, void* d_ws, size_t ws_size,
                              hipStream_t stream) {
  const float* muTE  = (const float*)d_in[0];
  const float* covTE = (const float*)d_in[1];
  const float* chol  = (const float*)d_in[2];
  float* out = (float*)d_out;

  (void)hipMemcpyAsync(out, muTE, (size_t)NB * NV * sizeof(float),
                       hipMemcpyDeviceToDevice, stream);

  float* cholTE = out + (size_t)NB * NV;
  const size_t nmat     = (size_t)NB * NV * NV;          // 33,554,432 elems
  const size_t lt_bytes = nmat * sizeof(unsigned short); // 64 MiB

  if (ws_size >= lt_bytes) {
    unsigned short* LT = (unsigned short*)d_ws;
    convert_LT_kernel<<<dim3(NB * 64), dim3(256), 0, stream>>>(chol, LT);
    fused_cholTE_v9<<<dim3(NB * 4), dim3(512), 0, stream>>>(covTE, chol, LT, cholTE);
  } else {
    fused_cholTE_fallback<<<dim3(NB * (NV / NC)), dim3(1024), 0, stream>>>(
        covTE, chol, cholTE);
  }
}

// Round 15
// 212.116 us; speedup vs baseline: 2.2492x; 1.1273x over previous
//
#include <hip/hip_runtime.h>
#include <hip/hip_bf16.h>

#define NV 512
#define NB 128
#define NC 64

typedef float fv4 __attribute__((ext_vector_type(4)));
typedef float fv2 __attribute__((ext_vector_type(2)));
typedef float f32x4 __attribute__((ext_vector_type(4)));
typedef short bf8 __attribute__((ext_vector_type(8)));            // 8 bf16 (MFMA A/B frag)
typedef unsigned short u16x4 __attribute__((ext_vector_type(4)));
typedef unsigned short u16x8 __attribute__((ext_vector_type(8)));
typedef unsigned u32x2 __attribute__((ext_vector_type(2)));
typedef unsigned u32x4 __attribute__((ext_vector_type(4)));

// f32 -> bf16 RNE, scalar
__device__ __forceinline__ unsigned short f2bf(float f) {
  unsigned u = __builtin_bit_cast(unsigned, f);
  u += 0x7fffu + ((u >> 16) & 1u);
  return (unsigned short)(u >> 16);
}

// packed f32x2 -> bf16x2 (v_cvt_pk_bf16_f32)
__device__ __forceinline__ unsigned cvt2(float lo, float hi) {
  __hip_bfloat162 h = __float22bfloat162_rn(make_float2(lo, hi));
  unsigned r;
  __builtin_memcpy(&r, &h, sizeof(r));
  return r;
}

__device__ __forceinline__ bf8 pack8(fv4 a0, fv4 a1) {
  u32x4 r;
  r[0] = cvt2(a0[0], a0[1]);
  r[1] = cvt2(a0[2], a0[3]);
  r[2] = cvt2(a1[0], a1[1]);
  r[3] = cvt2(a1[2], a1[3]);
  return __builtin_bit_cast(bf8, r);
}

// panel: [cols][512 rows] bf16, 1KB per col; XOR swizzle on 16B granules
__device__ __forceinline__ int swzL(int c, int r) {
  return ((c << 10) + (r << 1)) ^ ((c & 7) << 4);
}
// fallback staging layout
__device__ __forceinline__ int swzC(int j, int ii) {
  return ((j << 6) + (ii << 1)) ^ ((j & 3) << 4);
}

__device__ __forceinline__ void gload_lds16(const void* g, void* l) {
  __builtin_amdgcn_global_load_lds(
      (const __attribute__((address_space(1))) unsigned int*)g,
      (__attribute__((address_space(3))) unsigned int*)l, 16, 0, 0);
}

// ---------------------------------------------------------------------------
// Convert kernels
// ---------------------------------------------------------------------------
__global__ __launch_bounds__(256, 4)
void conv_f32_bf16_kernel(const float* __restrict__ src, unsigned short* __restrict__ dst) {
  const size_t i8 = ((size_t)blockIdx.x * 256 + threadIdx.x) * 8;
  fv4 a0 = *(const fv4*)(src + i8);
  fv4 a1 = *(const fv4*)(src + i8 + 4);
  u32x4 r;
  r[0] = cvt2(a0[0], a0[1]); r[1] = cvt2(a0[2], a0[3]);
  r[2] = cvt2(a1[0], a1[1]); r[3] = cvt2(a1[2], a1[3]);
  *(u32x4*)(dst + i8) = r;
}

// chol f32 -> LR bf16 (row-major, optional) + LT bf16 (transposed)
__global__ __launch_bounds__(256, 4)
void convert_LT_kernel(const float* __restrict__ chol,
                       unsigned short* __restrict__ LT,
                       unsigned short* __restrict__ LR) {
  __shared__ unsigned short T[64][72];
  const int bid = blockIdx.x;
  const int b  = bid >> 6;
  const int t  = bid & 63;
  const int ti = t >> 3, tj = t & 7;

  const float* src = chol + ((size_t)b * NV + ti * 64) * NV + tj * 64;
  {
    const int r0 = threadIdx.x >> 4;
    const int c4 = (threadIdx.x & 15) * 4;
    #pragma unroll
    for (int p = 0; p < 4; ++p) {
      const int r = p * 16 + r0;
      fv4 v = *(const fv4*)(src + (size_t)r * NV + c4);
      T[c4 + 0][r] = f2bf(v[0]);
      T[c4 + 1][r] = f2bf(v[1]);
      T[c4 + 2][r] = f2bf(v[2]);
      T[c4 + 3][r] = f2bf(v[3]);
      if (LR) {
        u32x2 pk; pk[0] = cvt2(v[0], v[1]); pk[1] = cvt2(v[2], v[3]);
        *(u32x2*)(LR + ((size_t)b * NV + ti * 64 + r) * NV + tj * 64 + c4) = pk;
      }
    }
  }
  __syncthreads();
  unsigned short* dst = LT + ((size_t)b * NV + tj * 64) * NV + ti * 64;
  const int c  = threadIdx.x >> 2;
  const int k8 = (threadIdx.x & 3) * 16;
  u16x8 o0, o1;
  #pragma unroll
  for (int q = 0; q < 8; ++q) { o0[q] = T[c][k8 + q]; o1[q] = T[c][k8 + 8 + q]; }
  *(u16x8*)(dst + (size_t)c * NV + k8)     = o0;
  *(u16x8*)(dst + (size_t)c * NV + k8 + 8) = o1;
}

// ---------------------------------------------------------------------------
// v10 main kernel: v8 geometry (512 thr, 2 waves/SIMD, dual 64-col panels,
// 128 AGPR acc) + PER-WAVE async A-staging via global_load_lds into a
// private 4KB buffer. Zero barriers in the K-loop; next tile's DMA flies
// under the 32-MFMA block; A-loads cost no VGPRs.
// LDS = 128KB panels + 8 x 4KB wave buffers = 160KB (full pool, 1 WG/CU).
// ---------------------------------------------------------------------------
__device__ __forceinline__ void stageA10(const unsigned short* A, int t, char* buf,
                                         int w, int lane) {
  const int row = lane >> 2;          // 0..15 within 16-row chunk
  const int ko  = (lane & 3) * 8;     // k offset (elems)
  #pragma unroll
  for (int pi = 0; pi < 4; ++pi) {
    const unsigned short* src = A + (size_t)(w * 64 + pi * 16 + row) * NV + t * 32 + ko;
    gload_lds16(src, buf + pi * 1024);
  }
}

__device__ __forceinline__ void phase_v10(const unsigned short* Abase,
                                          const char* H, char* buf,
                                          f32x4 (&acc0)[4][4], f32x4 (&acc1)[4][4],
                                          int w, int lane, int lr, int lq) {
  stageA10(Abase, 0, buf, w, lane);
  #pragma unroll 2
  for (int t = 0; t < 16; ++t) {
    const int kbase = t * 32 + lq * 8;
    // wait own DMA (per-wave; no barrier)
    asm volatile("s_waitcnt vmcnt(0)" ::: "memory");
    bf8 a[4];
    #pragma unroll
    for (int m = 0; m < 4; ++m)
      a[m] = *(const bf8*)(buf + (m * 16 + lr) * 64 + lq * 16);
    // issue next tile's DMA: after the A ds_reads (must-alias keeps order),
    // before the MFMA block (310 cyc/SIMD hides the ~250cyc L2 latency).
    if (t + 1 < 16) stageA10(Abase, t + 1, buf, w, lane);
    bf8 b0[4];
    #pragma unroll
    for (int n = 0; n < 4; ++n)
      b0[n] = *(const bf8*)(H + swzL(n * 16 + lr, kbase));
    #pragma unroll
    for (int m = 0; m < 4; ++m)
      #pragma unroll
      for (int n = 0; n < 4; ++n)
        acc0[m][n] = __builtin_amdgcn_mfma_f32_16x16x32_bf16(a[m], b0[n], acc0[m][n], 0, 0, 0);
    bf8 b1[4];
    #pragma unroll
    for (int n = 0; n < 4; ++n)
      b1[n] = *(const bf8*)(H + swzL(64 + n * 16 + lr, kbase));
    #pragma unroll
    for (int m = 0; m < 4; ++m)
      #pragma unroll
      for (int n = 0; n < 4; ++n)
        acc1[m][n] = __builtin_amdgcn_mfma_f32_16x16x32_bf16(a[m], b1[n], acc1[m][n], 0, 0, 0);
  }
}

__global__ __launch_bounds__(512, 2)
void fused_cholTE_v10(const unsigned short* __restrict__ CV,
                      const unsigned short* __restrict__ LR,
                      const unsigned short* __restrict__ LT,
                      float* __restrict__ out) {
  __shared__ __align__(16) char lds[163840];
  char* H = lds;                          // 128 cols x 1KB: cholC -> T1 -> phi

  const int tid  = threadIdx.x;
  const int w    = tid >> 6;              // wave 0..7
  const int lane = tid & 63;
  const int lr   = lane & 15;
  const int lq   = lane >> 4;
  char* buf = lds + 131072 + w * 4096;    // private per-wave A buffer

  const int bid = blockIdx.x;
  const int xcd = bid & 7;
  const int s   = bid >> 3;               // 0..63
  const int b   = xcd * 16 + (s >> 2);    // batch
  const int c0  = (s & 3) * 128;          // column pair base

  const unsigned short* CVb = CV + (size_t)b * NV * NV;
  const unsigned short* LRb = LR + (size_t)b * NV * NV;
  const unsigned short* LTb = LT + (size_t)b * NV * NV;
  float*                Ob  = out + (size_t)b * NV * NV;

  f32x4 acc0[4][4], acc1[4][4];

  // ---- stage both cholC panels: LT rows c0..c0+127 -> H (source-swizzled)
  #pragma unroll
  for (int cc = 0; cc < 16; ++cc) {
    const int c = cc * 8 + w;
    const unsigned short* src = LTb + (size_t)(c0 + c) * NV + ((lane ^ (c & 7)) * 8);
    gload_lds16(src, H + c * 1024);
  }
  asm volatile("s_waitcnt vmcnt(0)" ::: "memory");
  __syncthreads();   // barrier 1: cholC panels ready

  // ---- Phase B: T1 = CV @ cholC
  #pragma unroll
  for (int m = 0; m < 4; ++m)
    #pragma unroll
    for (int n = 0; n < 4; ++n) { acc0[m][n] = (f32x4)0.f; acc1[m][n] = (f32x4)0.f; }
  phase_v10(CVb, H, buf, acc0, acc1, w, lane, lr, lq);
  __syncthreads();   // barrier 2: done reading cholC

  // T1 -> H (overwrite)
  #pragma unroll
  for (int m = 0; m < 4; ++m) {
    #pragma unroll
    for (int n = 0; n < 4; ++n) {
      const int rrow = w * 64 + m * 16 + lq * 4;
      f32x4 a = acc0[m][n];
      u32x2 pk; pk[0] = cvt2(a[0], a[1]); pk[1] = cvt2(a[2], a[3]);
      *(u32x2*)(H + swzL(n * 16 + lr, rrow)) = pk;
      a = acc1[m][n];
      pk[0] = cvt2(a[0], a[1]); pk[1] = cvt2(a[2], a[3]);
      *(u32x2*)(H + swzL(64 + n * 16 + lr, rrow)) = pk;
    }
  }
  __syncthreads();   // barrier 3: T1 panels ready

  // ---- Phase C: phi = LT-rows @ T1 (masked)
  #pragma unroll
  for (int m = 0; m < 4; ++m)
    #pragma unroll
    for (int n = 0; n < 4; ++n) { acc0[m][n] = (f32x4)0.f; acc1[m][n] = (f32x4)0.f; }
  phase_v10(LTb, H, buf, acc0, acc1, w, lane, lr, lq);
  __syncthreads();   // barrier 4: done reading T1

  // mask (strict lower=1, diag=0.5, upper=0); phi -> H (overwrite)
  #pragma unroll
  for (int jt = 0; jt < 4; ++jt) {
    #pragma unroll
    for (int n = 0; n < 4; ++n) {
      const int j0 = w * 64 + jt * 16 + lq * 4;
      const int gk0 = c0 + n * 16 + lr;
      const int gk1 = gk0 + 64;
      f32x4 a = acc0[jt][n];
      float f[4];
      #pragma unroll
      for (int q = 0; q < 4; ++q) {
        const int j = j0 + q;
        f[q] = (j > gk0) ? a[q] : ((j == gk0) ? 0.5f * a[q] : 0.f);
      }
      u32x2 pk; pk[0] = cvt2(f[0], f[1]); pk[1] = cvt2(f[2], f[3]);
      *(u32x2*)(H + swzL(n * 16 + lr, j0)) = pk;
      a = acc1[jt][n];
      #pragma unroll
      for (int q = 0; q < 4; ++q) {
        const int j = j0 + q;
        f[q] = (j > gk1) ? a[q] : ((j == gk1) ? 0.5f * a[q] : 0.f);
      }
      pk[0] = cvt2(f[0], f[1]); pk[1] = cvt2(f[2], f[3]);
      *(u32x2*)(H + swzL(64 + n * 16 + lr, j0)) = pk;
    }
  }
  __syncthreads();   // barrier 5: phi panels ready

  // ---- Phase D: out = -LR @ phi
  #pragma unroll
  for (int m = 0; m < 4; ++m)
    #pragma unroll
    for (int n = 0; n < 4; ++n) { acc0[m][n] = (f32x4)0.f; acc1[m][n] = (f32x4)0.f; }
  phase_v10(LRb, H, buf, acc0, acc1, w, lane, lr, lq);

  #pragma unroll
  for (int m = 0; m < 4; ++m) {
    const int i0 = w * 64 + m * 16 + lq * 4;
    #pragma unroll
    for (int n = 0; n < 4; ++n) {
      const int col = c0 + n * 16 + lr;
      f32x4 a = acc0[m][n];
      #pragma unroll
      for (int q = 0; q < 4; ++q)
        Ob[(size_t)(i0 + q) * NV + col] = -a[q];
      a = acc1[m][n];
      #pragma unroll
      for (int q = 0; q < 4; ++q)
        Ob[(size_t)(i0 + q) * NV + col + 64] = -a[q];
    }
  }
}

// ---------------------------------------------------------------------------
// v9 (R13, verified 239us): LT-only path for 64MB <= ws < 192MB
// ---------------------------------------------------------------------------
__device__ __forceinline__ void phase_v9_f32(const float* Abase,
                                             const char* H,
                                             f32x4 (&acc0)[4][4], f32x4 (&acc1)[4][4],
                                             int w, int lr, int lq) {
  const float* rA = Abase + (size_t)(w * 64 + lr) * NV + lq * 8;
  #pragma unroll 2
  for (int t = 0; t < 16; ++t) {
    const int kbase = t * 32 + lq * 8;
    bf8 a[4];
    #pragma unroll
    for (int m = 0; m < 4; ++m) {
      fv4 f0 = *(const fv4*)(rA + (size_t)(m * 16) * NV + t * 32);
      fv4 f1 = *(const fv4*)(rA + (size_t)(m * 16) * NV + t * 32 + 4);
      a[m] = pack8(f0, f1);
    }
    bf8 b0[4];
    #pragma unroll
    for (int n = 0; n < 4; ++n)
      b0[n] = *(const bf8*)(H + swzL(n * 16 + lr, kbase));
    #pragma unroll
    for (int m = 0; m < 4; ++m)
      #pragma unroll
      for (int n = 0; n < 4; ++n)
        acc0[m][n] = __builtin_amdgcn_mfma_f32_16x16x32_bf16(a[m], b0[n], acc0[m][n], 0, 0, 0);
    bf8 b1[4];
    #pragma unroll
    for (int n = 0; n < 4; ++n)
      b1[n] = *(const bf8*)(H + swzL(64 + n * 16 + lr, kbase));
    #pragma unroll
    for (int m = 0; m < 4; ++m)
      #pragma unroll
      for (int n = 0; n < 4; ++n)
        acc1[m][n] = __builtin_amdgcn_mfma_f32_16x16x32_bf16(a[m], b1[n], acc1[m][n], 0, 0, 0);
  }
}

__device__ __forceinline__ void phase_v9_bf16(const unsigned short* Abase,
                                              const char* H,
                                              f32x4 (&acc0)[4][4], f32x4 (&acc1)[4][4],
                                              int w, int lr, int lq) {
  const unsigned short* rA = Abase + (size_t)(w * 64 + lr) * NV + lq * 8;
  #pragma unroll 2
  for (int t = 0; t < 16; ++t) {
    const int kbase = t * 32 + lq * 8;
    bf8 a[4];
    #pragma unroll
    for (int m = 0; m < 4; ++m)
      a[m] = *(const bf8*)(rA + (size_t)(m * 16) * NV + t * 32);
    bf8 b0[4];
    #pragma unroll
    for (int n = 0; n < 4; ++n)
      b0[n] = *(const bf8*)(H + swzL(n * 16 + lr, kbase));
    #pragma unroll
    for (int m = 0; m < 4; ++m)
      #pragma unroll
      for (int n = 0; n < 4; ++n)
        acc0[m][n] = __builtin_amdgcn_mfma_f32_16x16x32_bf16(a[m], b0[n], acc0[m][n], 0, 0, 0);
    bf8 b1[4];
    #pragma unroll
    for (int n = 0; n < 4; ++n)
      b1[n] = *(const bf8*)(H + swzL(64 + n * 16 + lr, kbase));
    #pragma unroll
    for (int m = 0; m < 4; ++m)
      #pragma unroll
      for (int n = 0; n < 4; ++n)
        acc1[m][n] = __builtin_amdgcn_mfma_f32_16x16x32_bf16(a[m], b1[n], acc1[m][n], 0, 0, 0);
  }
}

__global__ __launch_bounds__(512, 2)
void fused_cholTE_v9(const float* __restrict__ covTE,
                     const float* __restrict__ chol,
                     const unsigned short* __restrict__ LT,
                     float* __restrict__ out) {
  __shared__ __align__(16) char H[131072];

  const int tid  = threadIdx.x;
  const int w    = tid >> 6;
  const int lane = tid & 63;
  const int lr   = lane & 15;
  const int lq   = lane >> 4;

  const int bid = blockIdx.x;
  const int xcd = bid & 7;
  const int s   = bid >> 3;
  const int b   = xcd * 16 + (s >> 2);
  const int c0  = (s & 3) * 128;

  const float*          Cb  = covTE + (size_t)b * NV * NV;
  const float*          Lb  = chol  + (size_t)b * NV * NV;
  const unsigned short* LTb = LT    + (size_t)b * NV * NV;
  float*                Ob  = out   + (size_t)b * NV * NV;

  f32x4 acc0[4][4], acc1[4][4];

  #pragma unroll
  for (int cc = 0; cc < 16; ++cc) {
    const int c = cc * 8 + w;
    const unsigned short* src = LTb + (size_t)(c0 + c) * NV + ((lane ^ (c & 7)) * 8);
    gload_lds16(src, H + c * 1024);
  }
  asm volatile("s_waitcnt vmcnt(0)" ::: "memory");
  __syncthreads();

  #pragma unroll
  for (int m = 0; m < 4; ++m)
    #pragma unroll
    for (int n = 0; n < 4; ++n) { acc0[m][n] = (f32x4)0.f; acc1[m][n] = (f32x4)0.f; }
  phase_v9_f32(Cb, H, acc0, acc1, w, lr, lq);
  __syncthreads();

  #pragma unroll
  for (int m = 0; m < 4; ++m) {
    #pragma unroll
    for (int n = 0; n < 4; ++n) {
      const int rrow = w * 64 + m * 16 + lq * 4;
      f32x4 a = acc0[m][n];
      u32x2 pk; pk[0] = cvt2(a[0], a[1]); pk[1] = cvt2(a[2], a[3]);
      *(u32x2*)(H + swzL(n * 16 + lr, rrow)) = pk;
      a = acc1[m][n];
      pk[0] = cvt2(a[0], a[1]); pk[1] = cvt2(a[2], a[3]);
      *(u32x2*)(H + swzL(64 + n * 16 + lr, rrow)) = pk;
    }
  }
  __syncthreads();

  #pragma unroll
  for (int m = 0; m < 4; ++m)
    #pragma unroll
    for (int n = 0; n < 4; ++n) { acc0[m][n] = (f32x4)0.f; acc1[m][n] = (f32x4)0.f; }
  phase_v9_bf16(LTb, H, acc0, acc1, w, lr, lq);
  __syncthreads();

  #pragma unroll
  for (int jt = 0; jt < 4; ++jt) {
    #pragma unroll
    for (int n = 0; n < 4; ++n) {
      const int j0 = w * 64 + jt * 16 + lq * 4;
      const int gk0 = c0 + n * 16 + lr;
      const int gk1 = gk0 + 64;
      f32x4 a = acc0[jt][n];
      float f[4];
      #pragma unroll
      for (int q = 0; q < 4; ++q) {
        const int j = j0 + q;
        f[q] = (j > gk0) ? a[q] : ((j == gk0) ? 0.5f * a[q] : 0.f);
      }
      u32x2 pk; pk[0] = cvt2(f[0], f[1]); pk[1] = cvt2(f[2], f[3]);
      *(u32x2*)(H + swzL(n * 16 + lr, j0)) = pk;
      a = acc1[jt][n];
      #pragma unroll
      for (int q = 0; q < 4; ++q) {
        const int j = j0 + q;
        f[q] = (j > gk1) ? a[q] : ((j == gk1) ? 0.5f * a[q] : 0.f);
      }
      pk[0] = cvt2(f[0], f[1]); pk[1] = cvt2(f[2], f[3]);
      *(u32x2*)(H + swzL(64 + n * 16 + lr, j0)) = pk;
    }
  }
  __syncthreads();

  #pragma unroll
  for (int m = 0; m < 4; ++m)
    #pragma unroll
    for (int n = 0; n < 4; ++n) { acc0[m][n] = (f32x4)0.f; acc1[m][n] = (f32x4)0.f; }
  phase_v9_f32(Lb, H, acc0, acc1, w, lr, lq);

  #pragma unroll
  for (int m = 0; m < 4; ++m) {
    const int i0 = w * 64 + m * 16 + lq * 4;
    #pragma unroll
    for (int n = 0; n < 4; ++n) {
      const int col = c0 + n * 16 + lr;
      f32x4 a = acc0[m][n];
      #pragma unroll
      for (int q = 0; q < 4; ++q)
        Ob[(size_t)(i0 + q) * NV + col] = -a[q];
      a = acc1[m][n];
      #pragma unroll
      for (int q = 0; q < 4; ++q)
        Ob[(size_t)(i0 + q) * NV + col + 64] = -a[q];
    }
  }
}

// ---------------------------------------------------------------------------
// No-workspace fallback (R1 form)
// ---------------------------------------------------------------------------
__global__ __launch_bounds__(1024, 1)
void fused_cholTE_fallback(const float* __restrict__ covTE,
                           const float* __restrict__ chol,
                           float* __restrict__ out) {
  __shared__ __align__(16) char lds[131072];
  char* sB0 = lds;
  char* sB1 = lds + 65536;
  char* sCh = lds;

  const int tid  = threadIdx.x;
  const int w    = tid >> 6;
  const int lane = tid & 63;
  const int lr   = lane & 15;
  const int lq   = lane >> 4;

  const int bid = blockIdx.x;
  const int xcd = bid & 7;
  const int s   = bid >> 3;
  const int b   = xcd * 16 + (s >> 3);
  const int c0  = (s & 7) * NC;

  const float* Cb = covTE + (size_t)b * NV * NV;
  const float* Lb = chol  + (size_t)b * NV * NV;
  float*       Ob = out   + (size_t)b * NV * NV;

  {
    const int rr = tid >> 4;
    const int cc = (tid & 15) * 4;
    #pragma unroll
    for (int p = 0; p < 8; ++p) {
      const int r = p * 64 + rr;
      fv4 v = *(const fv4*)(Lb + (size_t)r * NV + c0 + cc);
      *(unsigned short*)(sB0 + swzL(cc + 0, r)) = f2bf(v[0]);
      *(unsigned short*)(sB0 + swzL(cc + 1, r)) = f2bf(v[1]);
      *(unsigned short*)(sB0 + swzL(cc + 2, r)) = f2bf(v[2]);
      *(unsigned short*)(sB0 + swzL(cc + 3, r)) = f2bf(v[3]);
    }
  }
  __syncthreads();

  f32x4 acc[2][4];
  #pragma unroll
  for (int m = 0; m < 2; ++m)
    #pragma unroll
    for (int n = 0; n < 4; ++n) acc[m][n] = (f32x4)0.f;

  for (int kb = 0; kb < 16; ++kb) {
    const int kbase = kb * 32 + lq * 8;
    bf8 bfr[4];
    #pragma unroll
    for (int n = 0; n < 4; ++n)
      bfr[n] = *(const bf8*)(sB0 + swzL(n * 16 + lr, kbase));
    #pragma unroll
    for (int m = 0; m < 2; ++m) {
      const float* p = Cb + (size_t)(w * 32 + m * 16 + lr) * NV + kbase;
      fv4 a0 = *(const fv4*)p;
      fv4 a1 = *(const fv4*)(p + 4);
      bf8 af = pack8(a0, a1);
      #pragma unroll
      for (int n = 0; n < 4; ++n)
        acc[m][n] = __builtin_amdgcn_mfma_f32_16x16x32_bf16(af, bfr[n], acc[m][n], 0, 0, 0);
    }
  }
  #pragma unroll
  for (int m = 0; m < 2; ++m) {
    #pragma unroll
    for (int n = 0; n < 4; ++n) {
      f32x4 a = acc[m][n];
      u32x2 pk; pk[0] = cvt2(a[0], a[1]); pk[1] = cvt2(a[2], a[3]);
      *(u32x2*)(sB1 + swzL(n * 16 + lr, w * 32 + m * 16 + lq * 4)) = pk;
    }
  }
  __syncthreads();

  #pragma unroll
  for (int m = 0; m < 2; ++m)
    #pragma unroll
    for (int n = 0; n < 4; ++n) acc[m][n] = (f32x4)0.f;

  const int sj = (tid & 255) * 2;
  const int so = tid >> 8;

  fv2 raw[8];
  {
    const float* src = Lb + (size_t)(so * 8) * NV + sj;
    #pragma unroll
    for (int r = 0; r < 8; ++r) raw[r] = *(const fv2*)(src + (size_t)r * NV);
    u16x8 p0, p1;
    #pragma unroll
    for (int r = 0; r < 8; ++r) { p0[r] = f2bf(raw[r][0]); p1[r] = f2bf(raw[r][1]); }
    *(u16x8*)(sCh + swzC(sj + 0, so * 8)) = p0;
    *(u16x8*)(sCh + swzC(sj + 1, so * 8)) = p1;
  }
  __syncthreads();

  for (int ib = 0; ib < 16; ++ib) {
    if (ib + 1 < 16) {
      const float* src = Lb + (size_t)((ib + 1) * 32 + so * 8) * NV + sj;
      #pragma unroll
      for (int r = 0; r < 8; ++r) raw[r] = *(const fv2*)(src + (size_t)r * NV);
    }
    bf8 bt[4];
    #pragma unroll
    for (int n = 0; n < 4; ++n)
      bt[n] = *(const bf8*)(sB1 + swzL(n * 16 + lr, ib * 32 + lq * 8));
    #pragma unroll
    for (int jt = 0; jt < 2; ++jt) {
      bf8 af = *(const bf8*)(sCh + swzC(w * 32 + jt * 16 + lr, lq * 8));
      #pragma unroll
      for (int n = 0; n < 4; ++n)
        acc[jt][n] = __builtin_amdgcn_mfma_f32_16x16x32_bf16(af, bt[n], acc[jt][n], 0, 0, 0);
    }
    __syncthreads();
    if (ib + 1 < 16) {
      u16x8 p0, p1;
      #pragma unroll
      for (int r = 0; r < 8; ++r) { p0[r] = f2bf(raw[r][0]); p1[r] = f2bf(raw[r][1]); }
      *(u16x8*)(sCh + swzC(sj + 0, so * 8)) = p0;
      *(u16x8*)(sCh + swzC(sj + 1, so * 8)) = p1;
    }
    __syncthreads();
  }

  #pragma unroll
  for (int jt = 0; jt < 2; ++jt) {
    #pragma unroll
    for (int n = 0; n < 4; ++n) {
      f32x4 a = acc[jt][n];
      const int gk = c0 + n * 16 + lr;
      const int j0 = w * 32 + jt * 16 + lq * 4;
      float f[4];
      #pragma unroll
      for (int q = 0; q < 4; ++q) {
        const int j = j0 + q;
        f[q] = (j > gk) ? a[q] : ((j == gk) ? 0.5f * a[q] : 0.f);
      }
      u32x2 pk; pk[0] = cvt2(f[0], f[1]); pk[1] = cvt2(f[2], f[3]);
      *(u32x2*)(sB0 + swzL(n * 16 + lr, j0)) = pk;
    }
  }
  __syncthreads();

  #pragma unroll
  for (int m = 0; m < 2; ++m)
    #pragma unroll
    for (int n = 0; n < 4; ++n) acc[m][n] = (f32x4)0.f;

  for (int kb = 0; kb < 16; ++kb) {
    const int kbase = kb * 32 + lq * 8;
    bf8 bp[4];
    #pragma unroll
    for (int n = 0; n < 4; ++n)
      bp[n] = *(const bf8*)(sB0 + swzL(n * 16 + lr, kbase));
    #pragma unroll
    for (int m = 0; m < 2; ++m) {
      const float* p = Lb + (size_t)(w * 32 + m * 16 + lr) * NV + kbase;
      fv4 a0 = *(const fv4*)p;
      fv4 a1 = *(const fv4*)(p + 4);
      bf8 af = pack8(a0, a1);
      #pragma unroll
      for (int n = 0; n < 4; ++n)
        acc[m][n] = __builtin_amdgcn_mfma_f32_16x16x32_bf16(af, bp[n], acc[m][n], 0, 0, 0);
    }
  }
  #pragma unroll
  for (int m = 0; m < 2; ++m) {
    const int i0 = w * 32 + m * 16 + lq * 4;
    #pragma unroll
    for (int n = 0; n < 4; ++n) {
      f32x4 a = acc[m][n];
      const int col = c0 + n * 16 + lr;
      #pragma unroll
      for (int q = 0; q < 4; ++q)
        Ob[(size_t)(i0 + q) * NV + col] = -a[q];
    }
  }
}

extern "C" void kernel_launch(void* const* d_in, const int* in_sizes, int n_in,
                              void* d_out, int out_size, void* d_ws, size_t ws_size,
                              hipStream_t stream) {
  const float* muTE  = (const float*)d_in[0];
  const float* covTE = (const float*)d_in[1];
  const float* chol  = (const float*)d_in[2];
  float* out = (float*)d_out;

  (void)hipMemcpyAsync(out, muTE, (size_t)NB * NV * sizeof(float),
                       hipMemcpyDeviceToDevice, stream);

  float* cholTE = out + (size_t)NB * NV;
  const size_t nmat     = (size_t)NB * NV * NV;          // 33,554,432 elems
  const size_t lt_bytes = nmat * sizeof(unsigned short); // 64 MiB

  if (ws_size >= 3 * lt_bytes) {
    unsigned short* CV = (unsigned short*)d_ws;
    unsigned short* LR = CV + nmat;
    unsigned short* LT = LR + nmat;
    conv_f32_bf16_kernel<<<dim3(nmat / (256 * 8)), dim3(256), 0, stream>>>(covTE, CV);
    convert_LT_kernel<<<dim3(NB * 64), dim3(256), 0, stream>>>(chol, LT, LR);
    fused_cholTE_v10<<<dim3(NB * 4), dim3(512), 0, stream>>>(CV, LR, LT, cholTE);
  } else if (ws_size >= lt_bytes) {
    unsigned short* LT = (unsigned short*)d_ws;
    convert_LT_kernel<<<dim3(NB * 64), dim3(256), 0, stream>>>(chol, LT, nullptr);
    fused_cholTE_v9<<<dim3(NB * 4), dim3(512), 0, stream>>>(covTE, chol, LT, cholTE);
  } else {
    fused_cholTE_fallback<<<dim3(NB * (NV / NC)), dim3(1024), 0, stream>>>(
        covTE, chol, cholTE);
  }
}